// Round 7
// baseline (223.602 us; speedup 1.0000x reference)
//
#include <hip/hip_runtime.h>

#define BSZ 32
#define SLEN 512
#define CLEN 20
#define DMOD 256
#define NH 4
#define HDIM 64

typedef _Float16 half8 __attribute__((ext_vector_type(8)));
typedef _Float16 half4 __attribute__((ext_vector_type(4)));
typedef float float4v __attribute__((ext_vector_type(4)));

#define MFMA16(a, b, c) __builtin_amdgcn_mfma_f32_16x16x32_f16(a, b, c, 0, 0, 0)
// padded half8 index: groups of 16 half8 get stride 17 (breaks 256B-stride conflicts)
#define PG(fi) ((((fi) >> 4) * 17) + ((fi) & 15))

// ---------------- merged fp32->fp16 cast: 4 weight mats + embedding table ------
// blocks [0,128): weights (32 blocks each); blocks [128,2628): emb table
__global__ __launch_bounds__(256) void k_cast(
    const float* __restrict__ W0, const float* __restrict__ W1,
    const float* __restrict__ W2, const float* __restrict__ W3,
    const float* __restrict__ emb,
    _Float16* __restrict__ wh, _Float16* __restrict__ embh) {
  const int bid = blockIdx.x;
  const float* src;
  _Float16* dst;
  int idx;
  if (bid < 128) {
    const int z = bid >> 5;
    src = (z == 0) ? W0 : (z == 1) ? W1 : (z == 2) ? W2 : W3;
    dst = wh + (size_t)z * 65536;
    idx = ((bid & 31) * 256 + threadIdx.x) * 8;
  } else {
    src = emb;
    dst = embh;
    idx = ((bid - 128) * 256 + threadIdx.x) * 8;
  }
  float v[8];
  *(float4*)v = *(const float4*)(src + idx);
  *(float4*)(v + 4) = *(const float4*)(src + idx + 4);
  half8 h;
  #pragma unroll
  for (int i = 0; i < 8; ++i) h[i] = (_Float16)v[i];
  *(half8*)(dst + idx) = h;
}

// ---------------- fused: embedding sum + pos-enc -> fp16, AND mask bit-pack -----
// both phases use 8 rows/block on the same grid 2048; independent data
__global__ __launch_bounds__(256) void k_embmask(
    const int* __restrict__ seqs, const int* __restrict__ lengths,
    const _Float16* __restrict__ embh, const float* __restrict__ bias,
    const float* __restrict__ pe, _Float16* __restrict__ x,
    const int* __restrict__ masks, unsigned int* __restrict__ pk) {
  const int row0 = blockIdx.x * 8;
  // ---- phase 1: embedding (8 visit-rows, 32 lanes x 16B per 512B fp16 row) ----
  const int sub = threadIdx.x >> 5;
  const int hl = threadIdx.x & 31;
  const int row = row0 + sub;
  const int b = row >> 9, s = row & 511;
  __shared__ int codes[8][CLEN];
  if (threadIdx.x < 8 * CLEN)
    codes[threadIdx.x / CLEN][threadIdx.x % CLEN] = seqs[row0 * CLEN + threadIdx.x];
  __syncthreads();
  const int pos = (s < lengths[b]) ? (s + 1) : 0;
  const int d = hl * 8;
  float acc[8];
  *(float4*)acc = *(const float4*)(bias + d);
  *(float4*)(acc + 4) = *(const float4*)(bias + d + 4);
  const float4 pv0 = *(const float4*)(pe + (size_t)pos * DMOD + d);
  const float4 pv1 = *(const float4*)(pe + (size_t)pos * DMOD + d + 4);
  acc[0] += pv0.x; acc[1] += pv0.y; acc[2] += pv0.z; acc[3] += pv0.w;
  acc[4] += pv1.x; acc[5] += pv1.y; acc[6] += pv1.z; acc[7] += pv1.w;
  #pragma unroll
  for (int c = 0; c < CLEN; ++c) {
    const half8 ev = *(const half8*)(embh + (size_t)codes[sub][c] * DMOD + d);
    #pragma unroll
    for (int i = 0; i < 8; ++i) acc[i] += (float)ev[i];
  }
  half8 hv;
  #pragma unroll
  for (int i = 0; i < 8; ++i) hv[i] = (_Float16)acc[i];
  *(half8*)(x + (size_t)row * DMOD + d) = hv;
  // ---- phase 2: mask bit-pack (8 (b,q) rows, coalesced 256B wave-reads) -------
  const int wv = threadIdx.x >> 6;
  const int lane = threadIdx.x & 63;
  #pragma unroll
  for (int p = 0; p < 16; ++p) {
    const int it = wv + p * 4;              // 0..63: row = it>>3, chunk = it&7
    const int r = row0 + (it >> 3);
    const int chunk = it & 7;
    const int m = masks[(size_t)r * SLEN + chunk * 64 + lane];
    const unsigned long long bal = __ballot(m != 0);
    if (lane == 0) {
      pk[(size_t)r * 16 + chunk * 2]     = (unsigned int)bal;
      pk[(size_t)r * 16 + chunk * 2 + 1] = (unsigned int)(bal >> 32);
    }
  }
}

// ---------------- QKV GEMM: fp16 MFMA, prefetch, vectorized epilogue ------------
__global__ __launch_bounds__(256) void k_gemm_qkv(
    const _Float16* __restrict__ A, const _Float16* __restrict__ Wb,
    _Float16* __restrict__ q, _Float16* __restrict__ k, _Float16* __restrict__ v) {
  const int z = blockIdx.z;
  _Float16* Cb = (z == 0) ? q : (z == 1) ? k : v;
  const _Float16* w_ = Wb + (size_t)z * 65536;
  const int m0 = blockIdx.x * 128;
  const int n0 = blockIdx.y * 128;
  const int tid = threadIdx.x;
  const int lane = tid & 63;
  const int w = tid >> 6;
  const int wm = (w >> 1) * 4;
  const int wn = (w & 1) * 4;
  __shared__ _Float16 smem[8704];               // 17 KB: staging; epilogue reuse
  half8* As = (half8*)(smem);
  half8* Ws = (half8*)(smem + 4096);
  float4v acc[4][4];
  #pragma unroll
  for (int i = 0; i < 4; ++i)
    #pragma unroll
    for (int j = 0; j < 4; ++j)
      acc[i][j] = (float4v){0.f, 0.f, 0.f, 0.f};
  int li_[2]; size_t ga_[2], gw_[2];
  #pragma unroll
  for (int p = 0; p < 2; ++p) {
    const int c = tid + p * 256;
    const int r = c & 127, qd = c >> 7;
    li_[p] = (r >> 4) * 64 + qd * 16 + (r & 15);
    ga_[p] = (size_t)(m0 + r) * DMOD + qd * 8;
    gw_[p] = (size_t)(n0 + r) * DMOD + qd * 8;
  }
  half8 pa[2], pw[2];
  #pragma unroll
  for (int p = 0; p < 2; ++p) {
    pa[p] = *(const half8*)(A + ga_[p]);
    pw[p] = *(const half8*)(w_ + gw_[p]);
  }
  for (int k0 = 0; k0 < DMOD; k0 += 32) {
    #pragma unroll
    for (int p = 0; p < 2; ++p) {
      As[li_[p]] = pa[p];
      Ws[li_[p]] = pw[p];
    }
    __syncthreads();
    if (k0 + 32 < DMOD) {
      #pragma unroll
      for (int p = 0; p < 2; ++p) {
        pa[p] = *(const half8*)(A + ga_[p] + k0 + 32);
        pw[p] = *(const half8*)(w_ + gw_[p] + k0 + 32);
      }
    }
    half8 af[4], wf[4];
    #pragma unroll
    for (int i = 0; i < 4; ++i) {
      af[i] = As[(wm + i) * 64 + lane];
      wf[i] = Ws[(wn + i) * 64 + lane];
    }
    #pragma unroll
    for (int i = 0; i < 4; ++i)
      #pragma unroll
      for (int j = 0; j < 4; ++j)
        acc[i][j] = MFMA16(af[i], wf[j], acc[i][j]);
    __syncthreads();
  }
  const int cr = (lane >> 4) * 4;
  const int cc = lane & 15;
  _Float16* Eh = smem;
  #pragma unroll
  for (int ip = 0; ip < 4; ++ip) {
    #pragma unroll
    for (int j = 0; j < 4; ++j) {
      const int col = (wn + j) * 16 + cc;
      #pragma unroll
      for (int r = 0; r < 4; ++r)
        Eh[((w >> 1) * 16 + cr + r) * 136 + col] = (_Float16)acc[ip][j][r];
    }
    __syncthreads();
    #pragma unroll
    for (int e = 0; e < 2; ++e) {
      const int idx = tid + e * 256;
      const int lr = idx >> 4;
      const int cg = idx & 15;
      const int gr = m0 + (lr >> 4) * 64 + ip * 16 + (lr & 15);
      *(half8*)(Cb + (size_t)gr * DMOD + n0 + cg * 8) =
          *(const half8*)&Eh[lr * 136 + cg * 8];
    }
    __syncthreads();
  }
}

// ---------------- per-bh transpose: v[bh][s][d] -> vt[bh][d][s] -----------------
// one 64x64 tile per block: grid (BSZ*NH, 8) -> 1024 blocks, 4 blocks/CU
__global__ __launch_bounds__(256) void k_vt(
    const _Float16* __restrict__ v, _Float16* __restrict__ vt) {
  const int bh = blockIdx.x;
  const size_t off = (size_t)bh * 32768;
  __shared__ _Float16 Th[64][66];
  const int tid = threadIdx.x;
  const int sc = blockIdx.y * 64;
  #pragma unroll
  for (int p = 0; p < 2; ++p) {
    const int lin = tid + p * 256;
    const int r = lin >> 3, g = lin & 7;
    *(half8*)&Th[r][g * 8] = *(const half8*)(v + off + (size_t)(sc + r) * 64 + g * 8);
  }
  __syncthreads();
  #pragma unroll
  for (int p = 0; p < 2; ++p) {
    const int lin = tid + p * 256;
    const int d = lin >> 3, sg = lin & 7;
    half8 hv;
    #pragma unroll
    for (int j = 0; j < 8; ++j) hv[j] = Th[sg * 8 + j][d];
    *(half8*)(vt + off + (size_t)d * 512 + sc + sg * 8) = hv;
  }
}

// ---------------- FC GEMM (fp32 out + fp16 residual), fp16 MFMA -----------------
__global__ __launch_bounds__(256) void k_gemm_fc(
    const _Float16* __restrict__ A, const _Float16* __restrict__ w_,
    float* __restrict__ C, const _Float16* __restrict__ res) {
  const int m0 = blockIdx.x * 128;
  const int n0 = blockIdx.y * 128;
  const int tid = threadIdx.x;
  const int lane = tid & 63;
  const int w = tid >> 6;
  const int wm = (w >> 1) * 4;
  const int wn = (w & 1) * 4;
  __shared__ half8 As[512], Ws[512];
  float4v acc[4][4];
  #pragma unroll
  for (int i = 0; i < 4; ++i)
    #pragma unroll
    for (int j = 0; j < 4; ++j)
      acc[i][j] = (float4v){0.f, 0.f, 0.f, 0.f};
  int li_[2]; size_t ga_[2], gw_[2];
  #pragma unroll
  for (int p = 0; p < 2; ++p) {
    const int c = tid + p * 256;
    const int r = c & 127, qd = c >> 7;
    li_[p] = (r >> 4) * 64 + qd * 16 + (r & 15);
    ga_[p] = (size_t)(m0 + r) * DMOD + qd * 8;
    gw_[p] = (size_t)(n0 + r) * DMOD + qd * 8;
  }
  half8 pa[2], pw[2];
  #pragma unroll
  for (int p = 0; p < 2; ++p) {
    pa[p] = *(const half8*)(A + ga_[p]);
    pw[p] = *(const half8*)(w_ + gw_[p]);
  }
  for (int k0 = 0; k0 < DMOD; k0 += 32) {
    #pragma unroll
    for (int p = 0; p < 2; ++p) {
      As[li_[p]] = pa[p];
      Ws[li_[p]] = pw[p];
    }
    __syncthreads();
    if (k0 + 32 < DMOD) {
      #pragma unroll
      for (int p = 0; p < 2; ++p) {
        pa[p] = *(const half8*)(A + ga_[p] + k0 + 32);
        pw[p] = *(const half8*)(w_ + gw_[p] + k0 + 32);
      }
    }
    half8 af[4], wf[4];
    #pragma unroll
    for (int i = 0; i < 4; ++i) {
      af[i] = As[(wm + i) * 64 + lane];
      wf[i] = Ws[(wn + i) * 64 + lane];
    }
    #pragma unroll
    for (int i = 0; i < 4; ++i)
      #pragma unroll
      for (int j = 0; j < 4; ++j)
        acc[i][j] = MFMA16(af[i], wf[j], acc[i][j]);
    __syncthreads();
  }
  const int cr = (lane >> 4) * 4;
  const int cc = lane & 15;
  #pragma unroll
  for (int i = 0; i < 4; ++i) {
    const int gm = m0 + (wm + i) * 16 + cr;
    #pragma unroll
    for (int j = 0; j < 4; ++j) {
      const int gc = n0 + (wn + j) * 16 + cc;
      #pragma unroll
      for (int r = 0; r < 4; ++r) {
        const size_t flat = (size_t)(gm + r) * DMOD + gc;
        C[flat] = acc[i][j][r] + (float)res[flat];
      }
    }
  }
}

// ---------------- MFMA attention per (bh, q-tile of 256), fp16 ------------------
// 512 threads = 2 q-halves x verified 4-wave structure; K/V staged ONCE per
// k-iter, consumed by both halves -> K/V^T traffic halves again (67 -> 33.5 MB).
// Grid 256 = 1 block/CU x 8 waves = 2 waves/SIMD (same TLP as q128 config).
__global__ __launch_bounds__(512, 1) void k_attn(
    const _Float16* __restrict__ q_, const _Float16* __restrict__ k_,
    const _Float16* __restrict__ vt, const unsigned int* __restrict__ pk,
    _Float16* __restrict__ o) {
  const int L = blockIdx.x;                     // 256 blocks
  const int bh = L >> 1;
  const int q0 = (L & 1) * 256;
  const size_t bhoff = (size_t)bh * 32768;
  __shared__ half8 QP[2][1088];                 // per-half Q staging, then P
  __shared__ half8 Ks[544], Vs[544];            // shared by both halves
  __shared__ unsigned long long Ms64[256];      // mask rows for 256 q
  __shared__ float Ps[2][4][128];
  __shared__ float lsum[256];
  const int tid = threadIdx.x;
  const int w8 = tid >> 6;                      // 0..7
  const int qh = w8 >> 2;                       // q-half
  const int w = w8 & 3;                         // k/d wave within half
  const int lane = tid & 63;
  const int l15 = lane & 15;
  const int quad = lane >> 4;
  // stage Q tile: 256 rows x 64 d -> per-half PG layout
  #pragma unroll
  for (int p = 0; p < 4; ++p) {
    const int lin = tid + p * 512;
    const int r = lin >> 3, g = lin & 7;
    const int rh = r >> 7, rl = r & 127;
    const int fi = (rl >> 4) * 128 + g * 16 + (rl & 15);
    QP[rh][PG(fi)] = *(const half8*)(q_ + bhoff + (size_t)(q0 + r) * 64 + g * 8);
  }
  __syncthreads();
  half8 qf[8][2];
  #pragma unroll
  for (int ns = 0; ns < 8; ++ns) {
    const int gq = ns * 8 + quad;
    qf[ns][0] = QP[qh][gq * 17 + l15];
    qf[ns][1] = QP[qh][(gq + 4) * 17 + l15];
  }
  float4v oacc[8];
  float lsw[8] = {0.f, 0.f, 0.f, 0.f, 0.f, 0.f, 0.f, 0.f};
  #pragma unroll
  for (int ns = 0; ns < 8; ++ns) oacc[ns] = (float4v){0.f, 0.f, 0.f, 0.f};
  const int ga0 = (w * 8 + quad) * 17 + l15;
  const int ga1 = (w * 8 + quad + 4) * 17 + l15;
  for (int kc = 0; kc < SLEN; kc += 64) {
    __syncthreads();
    {                                           // stage K/V: 512 half8 each
      const int r = tid >> 3, g = tid & 7;
      const int fi = PG((r >> 4) * 128 + g * 16 + (r & 15));
      Ks[fi] = *(const half8*)(k_ + bhoff + (size_t)(kc + r) * 64 + g * 8);
      Vs[fi] = *(const half8*)(vt + bhoff + (size_t)r * 512 + kc + g * 8);
    }
    ((unsigned int*)Ms64)[tid] =
        pk[((size_t)((bh >> 2) << 9) + q0 + (tid >> 1)) * 16 + (kc >> 5) + (tid & 1)];
    __syncthreads();
    const half8 ah0 = Ks[ga0], ah1 = Ks[ga1];
    #pragma unroll
    for (int ns = 0; ns < 8; ++ns) {
      float4v s = (float4v){0.f, 0.f, 0.f, 0.f};
      s = MFMA16(ah0, qf[ns][0], s);
      s = MFMA16(ah1, qf[ns][1], s);
      const int q = ns * 16 + l15;
      const unsigned long long mrow = Ms64[qh * 128 + q];
      const unsigned mbits = (unsigned)(mrow >> (w * 16 + quad * 4)) & 15u;
      half4 h4;
      #pragma unroll
      for (int r = 0; r < 4; ++r) {
        const float pe = ((mbits >> r) & 1u) ? __expf(s[r] * 0.125f) : 0.f;
        h4[r] = (_Float16)pe;
        lsw[ns] += pe;
      }
      const int hb = ((ns * 8 + w * 2 + (quad >> 1)) * 17 + l15) * 8 + (quad & 1) * 4;
      *(half4*)((_Float16*)QP[qh] + hb) = h4;
    }
    __syncthreads();
    const half8 vh0 = Vs[ga0], vh1 = Vs[ga1];
    #pragma unroll
    for (int ns = 0; ns < 8; ++ns) {
      const int pb0 = (ns * 8 + quad) * 17 + l15;
      const int pb1 = (ns * 8 + quad + 4) * 17 + l15;
      oacc[ns] = MFMA16(vh0, QP[qh][pb0], oacc[ns]);
      oacc[ns] = MFMA16(vh1, QP[qh][pb1], oacc[ns]);
    }
  }
  #pragma unroll
  for (int ns = 0; ns < 8; ++ns) {
    lsw[ns] += __shfl_xor(lsw[ns], 16);
    lsw[ns] += __shfl_xor(lsw[ns], 32);
  }
  __syncthreads();
  if (quad == 0) {
    #pragma unroll
    for (int ns = 0; ns < 8; ++ns) Ps[qh][w][ns * 16 + l15] = lsw[ns];
  }
  __syncthreads();
  if (tid < 256) {
    const int hh = tid >> 7, qq = tid & 127;
    lsum[tid] = Ps[hh][0][qq] + Ps[hh][1][qq] + Ps[hh][2][qq] + Ps[hh][3][qq];
  }
  __syncthreads();
  // epilogue: restage O tile [256 q][64 d] in LDS (stride 68), full-line stores
  const int b = bh >> 2, h = bh & 3;
  _Float16* Ot = (_Float16*)QP;                 // 256*68 = 17408 halfs = QP exactly
  #pragma unroll
  for (int ns = 0; ns < 8; ++ns) {
    const int q = qh * 128 + ns * 16 + l15;
    const float inv = 1.0f / lsum[q];
    half4 h4;
    #pragma unroll
    for (int r = 0; r < 4; ++r) h4[r] = (_Float16)(oacc[ns][r] * inv);
    *(half4*)&Ot[q * 68 + w * 16 + quad * 4] = h4;
  }
  __syncthreads();
  #pragma unroll
  for (int e = 0; e < 4; ++e) {
    const int idx = tid + e * 512;
    const int qq = idx >> 3, g = idx & 7;
    *(half8*)(o + ((size_t)(b * SLEN + q0 + qq)) * DMOD + h * HDIM + g * 8) =
        *(const half8*)&Ot[qq * 68 + g * 8];
  }
}

// ---------------- fused layer norm + zero invalid + triangular pooling ----------
// 32 rows/block: grid (32,16) = 512 blocks, 2 blocks/CU
__global__ __launch_bounds__(256) void k_lnpool(
    const float* __restrict__ Y, const int* __restrict__ lengths,
    const float* __restrict__ g, const float* __restrict__ bb,
    float* __restrict__ Up) {
  const int b = blockIdx.x;
  const int c = blockIdx.y;
  const int tid = threadIdx.x;
  const int w = tid >> 6;
  const int lane = tid & 63;
  __shared__ float Pl[4][4][DMOD];              // [wave][bin][d]
  const int len = lengths[b];
  const float inv4 = 4.0f / (float)len;
  float gg[4], bv[4];
  *(float4*)gg = *(const float4*)(g + lane * 4);
  *(float4*)bv = *(const float4*)(bb + lane * 4);
  float a[4][4] = {};                           // [bin][d-sub]
  for (int t = 0; t < 8; ++t) {
    const int r = c * 32 + t * 4 + w;
    float v[4];
    *(float4*)v = *(const float4*)(Y + ((size_t)b * SLEN + r) * DMOD + lane * 4);
    float sum = v[0] + v[1] + v[2] + v[3];
    float sq = v[0] * v[0] + v[1] * v[1] + v[2] * v[2] + v[3] * v[3];
    #pragma unroll
    for (int off = 32; off > 0; off >>= 1) {
      sum += __shfl_xor(sum, off);
      sq += __shfl_xor(sq, off);
    }
    const float mu = sum * (1.0f / DMOD);
    const float inv = rsqrtf(sq * (1.0f / DMOD) - mu * mu + 1e-5f);
    const bool valid = r < len;
    float ov[4];
    #pragma unroll
    for (int i = 0; i < 4; ++i)
      ov[i] = valid ? ((v[i] - mu) * inv * gg[i] + bv[i]) : 0.f;
    const float sv = (float)(r + 1) * inv4;
    #pragma unroll
    for (int m = 0; m < 4; ++m) {
      const float tm = 1.0f - fabsf(sv - (float)(m + 1)) * 0.25f;
      const float t2 = tm * tm;
      #pragma unroll
      for (int i = 0; i < 4; ++i) a[m][i] += t2 * ov[i];
    }
  }
  #pragma unroll
  for (int m = 0; m < 4; ++m)
    *(float4*)&Pl[w][m][lane * 4] = *(float4*)a[m];
  __syncthreads();
  #pragma unroll
  for (int e = 0; e < 4; ++e) {
    const int idx = tid + e * 256;
    const int m = idx >> 8, d = idx & 255;
    const float s = Pl[0][m][d] + Pl[1][m][d] + Pl[2][m][d] + Pl[3][m][d];
    Up[(((size_t)b * 16 + c) * 4 + m) * DMOD + d] = s;
  }
}

// ---------------- final [32,2048] partial-sum @ [1024,2]^T + bias ---------------
__global__ __launch_bounds__(256) void k_out(
    const float* __restrict__ Up, const float* __restrict__ ow,
    const float* __restrict__ ob, float* __restrict__ out) {
  const int b = blockIdx.x;
  const int tid = threadIdx.x;
  const int w = tid >> 6;
  const int lane = tid & 63;
  __shared__ float rr[8];
  float4 s = {0.f, 0.f, 0.f, 0.f};
  #pragma unroll
  for (int c = 0; c < 16; ++c) {
    const float4 u = *(const float4*)(Up + ((size_t)b * 16 + c) * 1024 + tid * 4);
    s.x += u.x; s.y += u.y; s.z += u.z; s.w += u.w;
  }
  const float4 w0 = *(const float4*)(ow + tid * 4);
  const float4 w1 = *(const float4*)(ow + 1024 + tid * 4);
  float acc0 = s.x * w0.x + s.y * w0.y + s.z * w0.z + s.w * w0.w;
  float acc1 = s.x * w1.x + s.y * w1.y + s.z * w1.z + s.w * w1.w;
  #pragma unroll
  for (int off = 32; off > 0; off >>= 1) {
    acc0 += __shfl_xor(acc0, off);
    acc1 += __shfl_xor(acc1, off);
  }
  if (lane == 0) { rr[w] = acc0; rr[4 + w] = acc1; }
  __syncthreads();
  if (tid == 0) {
    out[b * 2 + 0] = rr[0] + rr[1] + rr[2] + rr[3] + ob[0];
    out[b * 2 + 1] = rr[4] + rr[5] + rr[6] + rr[7] + ob[1];
  }
}

extern "C" void kernel_launch(void* const* d_in, const int* in_sizes, int n_in,
                              void* d_out, int out_size, void* d_ws, size_t ws_size,
                              hipStream_t stream) {
  const int* seqs     = (const int*)d_in[0];
  const int* masks    = (const int*)d_in[1];
  const int* lengths  = (const int*)d_in[2];
  const float* emb    = (const float*)d_in[5];
  const float* bias   = (const float*)d_in[6];
  const float* pe     = (const float*)d_in[7];
  const float* Wq     = (const float*)d_in[8];
  const float* Wk     = (const float*)d_in[9];
  const float* Wv     = (const float*)d_in[10];
  const float* Wfc    = (const float*)d_in[11];
  const float* ln_g   = (const float*)d_in[12];
  const float* ln_b   = (const float*)d_in[13];
  const float* out_w  = (const float*)d_in[14];
  const float* out_b  = (const float*)d_in[15];
  float* outp = (float*)d_out;

  const size_t NE = (size_t)BSZ * SLEN * DMOD;   // 4,194,304
  _Float16* q = (_Float16*)d_ws;
  _Float16* k = q + NE;
  _Float16* v = k + NE;
  _Float16* vt = v + NE;
  _Float16* x = vt + NE;
  _Float16* o = x + NE;
  _Float16* wh = o + NE;                         // 4*65536 halfs
  unsigned int* pk = (unsigned int*)(wh + 4 * 65536);
  float* Up = (float*)(pk + BSZ * SLEN * 16);    // [32][16][4][256] fp32 = 2 MB
  float* y = (float*)q;                          // alias: q,k dead after attn
  // fp16 emb table (10.24 MB) aliases q+k: dead before gemm_qkv writes them
  _Float16* embh = (_Float16*)d_ws;

  k_cast<<<2628, 256, 0, stream>>>(Wq, Wk, Wv, Wfc, emb, wh, embh);
  k_embmask<<<BSZ * SLEN / 8, 256, 0, stream>>>(seqs, lengths, embh, bias, pe, x,
                                                masks, pk);
  k_gemm_qkv<<<dim3(128, 2, 3), 256, 0, stream>>>(x, wh, q, k, v);
  k_vt<<<dim3(BSZ * NH, 8), 256, 0, stream>>>(v, vt);
  k_attn<<<BSZ * NH * (SLEN / 256), 512, 0, stream>>>(q, k, vt, pk, o);
  k_gemm_fc<<<dim3(128, 2), 256, 0, stream>>>(o, wh + 3 * 65536, y, x);
  k_lnpool<<<dim3(BSZ, 16), 256, 0, stream>>>(y, lengths, ln_g, ln_b, Up);
  k_out<<<BSZ, 256, 0, stream>>>(Up, out_w, out_b, outp);
}

// Round 8
// 222.445 us; speedup vs baseline: 1.0052x; 1.0052x over previous
//
#include <hip/hip_runtime.h>

#define BSZ 32
#define SLEN 512
#define CLEN 20
#define DMOD 256
#define NH 4
#define HDIM 64

typedef _Float16 half8 __attribute__((ext_vector_type(8)));
typedef _Float16 half4 __attribute__((ext_vector_type(4)));
typedef float float4v __attribute__((ext_vector_type(4)));

#define MFMA16(a, b, c) __builtin_amdgcn_mfma_f32_16x16x32_f16(a, b, c, 0, 0, 0)
// padded half8 index: groups of 16 half8 get stride 17 (breaks 256B-stride conflicts)
#define PG(fi) ((((fi) >> 4) * 17) + ((fi) & 15))

// ---------------- merged fp32->fp16 cast: 4 weight mats + embedding table ------
// blocks [0,128): weights (32 blocks each); blocks [128,2628): emb table
__global__ __launch_bounds__(256) void k_cast(
    const float* __restrict__ W0, const float* __restrict__ W1,
    const float* __restrict__ W2, const float* __restrict__ W3,
    const float* __restrict__ emb,
    _Float16* __restrict__ wh, _Float16* __restrict__ embh) {
  const int bid = blockIdx.x;
  const float* src;
  _Float16* dst;
  int idx;
  if (bid < 128) {
    const int z = bid >> 5;
    src = (z == 0) ? W0 : (z == 1) ? W1 : (z == 2) ? W2 : W3;
    dst = wh + (size_t)z * 65536;
    idx = ((bid & 31) * 256 + threadIdx.x) * 8;
  } else {
    src = emb;
    dst = embh;
    idx = ((bid - 128) * 256 + threadIdx.x) * 8;
  }
  float v[8];
  *(float4*)v = *(const float4*)(src + idx);
  *(float4*)(v + 4) = *(const float4*)(src + idx + 4);
  half8 h;
  #pragma unroll
  for (int i = 0; i < 8; ++i) h[i] = (_Float16)v[i];
  *(half8*)(dst + idx) = h;
}

// ---------------- fused: embedding sum + pos-enc -> fp16, AND mask bit-pack -----
// both phases use 8 rows/block on the same grid 2048; independent data
__global__ __launch_bounds__(256) void k_embmask(
    const int* __restrict__ seqs, const int* __restrict__ lengths,
    const _Float16* __restrict__ embh, const float* __restrict__ bias,
    const float* __restrict__ pe, _Float16* __restrict__ x,
    const int* __restrict__ masks, unsigned int* __restrict__ pk) {
  const int row0 = blockIdx.x * 8;
  // ---- phase 1: embedding (8 visit-rows, 32 lanes x 16B per 512B fp16 row) ----
  const int sub = threadIdx.x >> 5;
  const int hl = threadIdx.x & 31;
  const int row = row0 + sub;
  const int b = row >> 9, s = row & 511;
  __shared__ int codes[8][CLEN];
  if (threadIdx.x < 8 * CLEN)
    codes[threadIdx.x / CLEN][threadIdx.x % CLEN] = seqs[row0 * CLEN + threadIdx.x];
  __syncthreads();
  const int pos = (s < lengths[b]) ? (s + 1) : 0;
  const int d = hl * 8;
  float acc[8];
  *(float4*)acc = *(const float4*)(bias + d);
  *(float4*)(acc + 4) = *(const float4*)(bias + d + 4);
  const float4 pv0 = *(const float4*)(pe + (size_t)pos * DMOD + d);
  const float4 pv1 = *(const float4*)(pe + (size_t)pos * DMOD + d + 4);
  acc[0] += pv0.x; acc[1] += pv0.y; acc[2] += pv0.z; acc[3] += pv0.w;
  acc[4] += pv1.x; acc[5] += pv1.y; acc[6] += pv1.z; acc[7] += pv1.w;
  #pragma unroll
  for (int c = 0; c < CLEN; ++c) {
    const half8 ev = *(const half8*)(embh + (size_t)codes[sub][c] * DMOD + d);
    #pragma unroll
    for (int i = 0; i < 8; ++i) acc[i] += (float)ev[i];
  }
  half8 hv;
  #pragma unroll
  for (int i = 0; i < 8; ++i) hv[i] = (_Float16)acc[i];
  *(half8*)(x + (size_t)row * DMOD + d) = hv;
  // ---- phase 2: mask bit-pack (8 (b,q) rows, coalesced 256B wave-reads) -------
  const int wv = threadIdx.x >> 6;
  const int lane = threadIdx.x & 63;
  #pragma unroll
  for (int p = 0; p < 16; ++p) {
    const int it = wv + p * 4;              // 0..63: row = it>>3, chunk = it&7
    const int r = row0 + (it >> 3);
    const int chunk = it & 7;
    const int m = masks[(size_t)r * SLEN + chunk * 64 + lane];
    const unsigned long long bal = __ballot(m != 0);
    if (lane == 0) {
      pk[(size_t)r * 16 + chunk * 2]     = (unsigned int)bal;
      pk[(size_t)r * 16 + chunk * 2 + 1] = (unsigned int)(bal >> 32);
    }
  }
}

// ---------------- QKV GEMM: fp16 MFMA, prefetch, vectorized epilogue ------------
__global__ __launch_bounds__(256) void k_gemm_qkv(
    const _Float16* __restrict__ A, const _Float16* __restrict__ Wb,
    _Float16* __restrict__ q, _Float16* __restrict__ k, _Float16* __restrict__ v) {
  const int z = blockIdx.z;
  _Float16* Cb = (z == 0) ? q : (z == 1) ? k : v;
  const _Float16* w_ = Wb + (size_t)z * 65536;
  const int m0 = blockIdx.x * 128;
  const int n0 = blockIdx.y * 128;
  const int tid = threadIdx.x;
  const int lane = tid & 63;
  const int w = tid >> 6;
  const int wm = (w >> 1) * 4;
  const int wn = (w & 1) * 4;
  __shared__ _Float16 smem[8704];               // 17 KB: staging; epilogue reuse
  half8* As = (half8*)(smem);
  half8* Ws = (half8*)(smem + 4096);
  float4v acc[4][4];
  #pragma unroll
  for (int i = 0; i < 4; ++i)
    #pragma unroll
    for (int j = 0; j < 4; ++j)
      acc[i][j] = (float4v){0.f, 0.f, 0.f, 0.f};
  int li_[2]; size_t ga_[2], gw_[2];
  #pragma unroll
  for (int p = 0; p < 2; ++p) {
    const int c = tid + p * 256;
    const int r = c & 127, qd = c >> 7;
    li_[p] = (r >> 4) * 64 + qd * 16 + (r & 15);
    ga_[p] = (size_t)(m0 + r) * DMOD + qd * 8;
    gw_[p] = (size_t)(n0 + r) * DMOD + qd * 8;
  }
  half8 pa[2], pw[2];
  #pragma unroll
  for (int p = 0; p < 2; ++p) {
    pa[p] = *(const half8*)(A + ga_[p]);
    pw[p] = *(const half8*)(w_ + gw_[p]);
  }
  for (int k0 = 0; k0 < DMOD; k0 += 32) {
    #pragma unroll
    for (int p = 0; p < 2; ++p) {
      As[li_[p]] = pa[p];
      Ws[li_[p]] = pw[p];
    }
    __syncthreads();
    if (k0 + 32 < DMOD) {
      #pragma unroll
      for (int p = 0; p < 2; ++p) {
        pa[p] = *(const half8*)(A + ga_[p] + k0 + 32);
        pw[p] = *(const half8*)(w_ + gw_[p] + k0 + 32);
      }
    }
    half8 af[4], wf[4];
    #pragma unroll
    for (int i = 0; i < 4; ++i) {
      af[i] = As[(wm + i) * 64 + lane];
      wf[i] = Ws[(wn + i) * 64 + lane];
    }
    #pragma unroll
    for (int i = 0; i < 4; ++i)
      #pragma unroll
      for (int j = 0; j < 4; ++j)
        acc[i][j] = MFMA16(af[i], wf[j], acc[i][j]);
    __syncthreads();
  }
  const int cr = (lane >> 4) * 4;
  const int cc = lane & 15;
  _Float16* Eh = smem;
  #pragma unroll
  for (int ip = 0; ip < 4; ++ip) {
    #pragma unroll
    for (int j = 0; j < 4; ++j) {
      const int col = (wn + j) * 16 + cc;
      #pragma unroll
      for (int r = 0; r < 4; ++r)
        Eh[((w >> 1) * 16 + cr + r) * 136 + col] = (_Float16)acc[ip][j][r];
    }
    __syncthreads();
    #pragma unroll
    for (int e = 0; e < 2; ++e) {
      const int idx = tid + e * 256;
      const int lr = idx >> 4;
      const int cg = idx & 15;
      const int gr = m0 + (lr >> 4) * 64 + ip * 16 + (lr & 15);
      *(half8*)(Cb + (size_t)gr * DMOD + n0 + cg * 8) =
          *(const half8*)&Eh[lr * 136 + cg * 8];
    }
    __syncthreads();
  }
}

// ---------------- per-bh transpose: v[bh][s][d] -> vt[bh][d][s] -----------------
// one 64x64 tile per block: grid (BSZ*NH, 8) -> 1024 blocks, 4 blocks/CU
__global__ __launch_bounds__(256) void k_vt(
    const _Float16* __restrict__ v, _Float16* __restrict__ vt) {
  const int bh = blockIdx.x;
  const size_t off = (size_t)bh * 32768;
  __shared__ _Float16 Th[64][66];
  const int tid = threadIdx.x;
  const int sc = blockIdx.y * 64;
  #pragma unroll
  for (int p = 0; p < 2; ++p) {
    const int lin = tid + p * 256;
    const int r = lin >> 3, g = lin & 7;
    *(half8*)&Th[r][g * 8] = *(const half8*)(v + off + (size_t)(sc + r) * 64 + g * 8);
  }
  __syncthreads();
  #pragma unroll
  for (int p = 0; p < 2; ++p) {
    const int lin = tid + p * 256;
    const int d = lin >> 3, sg = lin & 7;
    half8 hv;
    #pragma unroll
    for (int j = 0; j < 8; ++j) hv[j] = Th[sg * 8 + j][d];
    *(half8*)(vt + off + (size_t)d * 512 + sc + sg * 8) = hv;
  }
}

// ---------------- FC GEMM (fp32 out + fp16 residual), fp16 MFMA -----------------
__global__ __launch_bounds__(256) void k_gemm_fc(
    const _Float16* __restrict__ A, const _Float16* __restrict__ w_,
    float* __restrict__ C, const _Float16* __restrict__ res) {
  const int m0 = blockIdx.x * 128;
  const int n0 = blockIdx.y * 128;
  const int tid = threadIdx.x;
  const int lane = tid & 63;
  const int w = tid >> 6;
  const int wm = (w >> 1) * 4;
  const int wn = (w & 1) * 4;
  __shared__ half8 As[512], Ws[512];
  float4v acc[4][4];
  #pragma unroll
  for (int i = 0; i < 4; ++i)
    #pragma unroll
    for (int j = 0; j < 4; ++j)
      acc[i][j] = (float4v){0.f, 0.f, 0.f, 0.f};
  int li_[2]; size_t ga_[2], gw_[2];
  #pragma unroll
  for (int p = 0; p < 2; ++p) {
    const int c = tid + p * 256;
    const int r = c & 127, qd = c >> 7;
    li_[p] = (r >> 4) * 64 + qd * 16 + (r & 15);
    ga_[p] = (size_t)(m0 + r) * DMOD + qd * 8;
    gw_[p] = (size_t)(n0 + r) * DMOD + qd * 8;
  }
  half8 pa[2], pw[2];
  #pragma unroll
  for (int p = 0; p < 2; ++p) {
    pa[p] = *(const half8*)(A + ga_[p]);
    pw[p] = *(const half8*)(w_ + gw_[p]);
  }
  for (int k0 = 0; k0 < DMOD; k0 += 32) {
    #pragma unroll
    for (int p = 0; p < 2; ++p) {
      As[li_[p]] = pa[p];
      Ws[li_[p]] = pw[p];
    }
    __syncthreads();
    if (k0 + 32 < DMOD) {
      #pragma unroll
      for (int p = 0; p < 2; ++p) {
        pa[p] = *(const half8*)(A + ga_[p] + k0 + 32);
        pw[p] = *(const half8*)(w_ + gw_[p] + k0 + 32);
      }
    }
    half8 af[4], wf[4];
    #pragma unroll
    for (int i = 0; i < 4; ++i) {
      af[i] = As[(wm + i) * 64 + lane];
      wf[i] = Ws[(wn + i) * 64 + lane];
    }
    #pragma unroll
    for (int i = 0; i < 4; ++i)
      #pragma unroll
      for (int j = 0; j < 4; ++j)
        acc[i][j] = MFMA16(af[i], wf[j], acc[i][j]);
    __syncthreads();
  }
  const int cr = (lane >> 4) * 4;
  const int cc = lane & 15;
  #pragma unroll
  for (int i = 0; i < 4; ++i) {
    const int gm = m0 + (wm + i) * 16 + cr;
    #pragma unroll
    for (int j = 0; j < 4; ++j) {
      const int gc = n0 + (wn + j) * 16 + cc;
      #pragma unroll
      for (int r = 0; r < 4; ++r) {
        const size_t flat = (size_t)(gm + r) * DMOD + gc;
        C[flat] = acc[i][j][r] + (float)res[flat];
      }
    }
  }
}

// ---------------- MFMA attention per (bh, q-tile of 128), fp16 ------------------
// Verified round-4/5/6 structure: q-tile 128, grid 512 = 2 blocks/CU (TLP:
// one block computes while the other stages). K/V^T traffic 67 MB.
__global__ __launch_bounds__(256, 2) void k_attn(
    const _Float16* __restrict__ q_, const _Float16* __restrict__ k_,
    const _Float16* __restrict__ vt, const unsigned int* __restrict__ pk,
    _Float16* __restrict__ o) {
  const int L = blockIdx.x;
  const int bh = (L & 7) * 16 + ((L >> 3) & 15);   // XCD-grouped bh (kept, neutral)
  const int q0 = (L >> 7) * 128;
  const size_t bhoff = (size_t)bh * 32768;
  __shared__ half8 QP[1088];                    // Q staging (128x64), then P (64x128)
  __shared__ half8 Ks[544], Vs[544];
  __shared__ unsigned long long Ms64[128];      // mask rows for 128 q
  __shared__ float Ps[4][128];
  __shared__ float lsum[128];
  const int tid = threadIdx.x;
  const int w = tid >> 6;
  const int lane = tid & 63;
  const int l15 = lane & 15;
  const int quad = lane >> 4;
  // stage Q tile: 128 rows x 64 d
  #pragma unroll
  for (int p = 0; p < 4; ++p) {
    const int lin = tid + p * 256;
    const int r = lin >> 3, g = lin & 7;
    const int fi = (r >> 4) * 128 + g * 16 + (r & 15);
    QP[PG(fi)] = *(const half8*)(q_ + bhoff + (size_t)(q0 + r) * 64 + g * 8);
  }
  __syncthreads();
  half8 qf[8][2];
  #pragma unroll
  for (int ns = 0; ns < 8; ++ns) {
    const int gq = ns * 8 + quad;
    qf[ns][0] = QP[gq * 17 + l15];
    qf[ns][1] = QP[(gq + 4) * 17 + l15];
  }
  float4v oacc[8];
  float lsw[8] = {0.f, 0.f, 0.f, 0.f, 0.f, 0.f, 0.f, 0.f};
  #pragma unroll
  for (int ns = 0; ns < 8; ++ns) oacc[ns] = (float4v){0.f, 0.f, 0.f, 0.f};
  for (int kc = 0; kc < SLEN; kc += 64) {
    __syncthreads();
    #pragma unroll
    for (int p = 0; p < 2; ++p) {
      const int lin = tid + p * 256;
      const int r = lin >> 3, g = lin & 7;
      const int fi = PG((r >> 4) * 128 + g * 16 + (r & 15));
      Ks[fi] = *(const half8*)(k_ + bhoff + (size_t)(kc + r) * 64 + g * 8);
      Vs[fi] = *(const half8*)(vt + bhoff + (size_t)r * 512 + kc + g * 8);
    }
    ((unsigned int*)Ms64)[tid] =
        pk[((size_t)((bh >> 2) << 9) + q0 + (tid >> 1)) * 16 + (kc >> 5) + (tid & 1)];
    __syncthreads();
    const int ga0 = (w * 8 + quad) * 17 + l15;
    const int ga1 = (w * 8 + quad + 4) * 17 + l15;
    const half8 ah0 = Ks[ga0], ah1 = Ks[ga1];
    #pragma unroll
    for (int ns = 0; ns < 8; ++ns) {
      float4v s = (float4v){0.f, 0.f, 0.f, 0.f};
      s = MFMA16(ah0, qf[ns][0], s);
      s = MFMA16(ah1, qf[ns][1], s);
      const int q = ns * 16 + l15;
      const unsigned long long mrow = Ms64[q];
      const unsigned mbits = (unsigned)(mrow >> (w * 16 + quad * 4)) & 15u;
      half4 h4;
      #pragma unroll
      for (int r = 0; r < 4; ++r) {
        const float pe = ((mbits >> r) & 1u) ? __expf(s[r] * 0.125f) : 0.f;
        h4[r] = (_Float16)pe;
        lsw[ns] += pe;
      }
      const int hb = ((ns * 8 + w * 2 + (quad >> 1)) * 17 + l15) * 8 + (quad & 1) * 4;
      *(half4*)((_Float16*)QP + hb) = h4;
    }
    __syncthreads();
    const half8 vh0 = Vs[ga0], vh1 = Vs[ga1];
    #pragma unroll
    for (int ns = 0; ns < 8; ++ns) {
      const int pb0 = (ns * 8 + quad) * 17 + l15;
      const int pb1 = (ns * 8 + quad + 4) * 17 + l15;
      oacc[ns] = MFMA16(vh0, QP[pb0], oacc[ns]);
      oacc[ns] = MFMA16(vh1, QP[pb1], oacc[ns]);
    }
  }
  #pragma unroll
  for (int ns = 0; ns < 8; ++ns) {
    lsw[ns] += __shfl_xor(lsw[ns], 16);
    lsw[ns] += __shfl_xor(lsw[ns], 32);
  }
  __syncthreads();
  if (quad == 0) {
    #pragma unroll
    for (int ns = 0; ns < 8; ++ns) Ps[w][ns * 16 + l15] = lsw[ns];
  }
  __syncthreads();
  if (tid < 128) lsum[tid] = Ps[0][tid] + Ps[1][tid] + Ps[2][tid] + Ps[3][tid];
  __syncthreads();
  // epilogue: restage O tile [128 q][64 d] in LDS (stride 68), full-line stores
  const int b = bh >> 2, h = bh & 3;
  _Float16* Ot = (_Float16*)QP;                 // 128*68 = 8704 halfs = QP exactly
  #pragma unroll
  for (int ns = 0; ns < 8; ++ns) {
    const int q = ns * 16 + l15;
    const float inv = 1.0f / lsum[q];
    half4 h4;
    #pragma unroll
    for (int r = 0; r < 4; ++r) h4[r] = (_Float16)(oacc[ns][r] * inv);
    *(half4*)&Ot[q * 68 + w * 16 + quad * 4] = h4;
  }
  __syncthreads();
  #pragma unroll
  for (int e = 0; e < 4; ++e) {
    const int idx = tid + e * 256;
    const int qq = idx >> 3, g = idx & 7;
    *(half8*)(o + ((size_t)(b * SLEN + q0 + qq)) * DMOD + h * HDIM + g * 8) =
        *(const half8*)&Ot[qq * 68 + g * 8];
  }
}

// ---------------- fused layer norm + zero invalid + triangular pooling ----------
// 32 rows/block: grid (32,16) = 512 blocks, 2 blocks/CU
__global__ __launch_bounds__(256) void k_lnpool(
    const float* __restrict__ Y, const int* __restrict__ lengths,
    const float* __restrict__ g, const float* __restrict__ bb,
    float* __restrict__ Up) {
  const int b = blockIdx.x;
  const int c = blockIdx.y;
  const int tid = threadIdx.x;
  const int w = tid >> 6;
  const int lane = tid & 63;
  __shared__ float Pl[4][4][DMOD];              // [wave][bin][d]
  const int len = lengths[b];
  const float inv4 = 4.0f / (float)len;
  float gg[4], bv[4];
  *(float4*)gg = *(const float4*)(g + lane * 4);
  *(float4*)bv = *(const float4*)(bb + lane * 4);
  float a[4][4] = {};                           // [bin][d-sub]
  for (int t = 0; t < 8; ++t) {
    const int r = c * 32 + t * 4 + w;
    float v[4];
    *(float4*)v = *(const float4*)(Y + ((size_t)b * SLEN + r) * DMOD + lane * 4);
    float sum = v[0] + v[1] + v[2] + v[3];
    float sq = v[0] * v[0] + v[1] * v[1] + v[2] * v[2] + v[3] * v[3];
    #pragma unroll
    for (int off = 32; off > 0; off >>= 1) {
      sum += __shfl_xor(sum, off);
      sq += __shfl_xor(sq, off);
    }
    const float mu = sum * (1.0f / DMOD);
    const float inv = rsqrtf(sq * (1.0f / DMOD) - mu * mu + 1e-5f);
    const bool valid = r < len;
    float ov[4];
    #pragma unroll
    for (int i = 0; i < 4; ++i)
      ov[i] = valid ? ((v[i] - mu) * inv * gg[i] + bv[i]) : 0.f;
    const float sv = (float)(r + 1) * inv4;
    #pragma unroll
    for (int m = 0; m < 4; ++m) {
      const float tm = 1.0f - fabsf(sv - (float)(m + 1)) * 0.25f;
      const float t2 = tm * tm;
      #pragma unroll
      for (int i = 0; i < 4; ++i) a[m][i] += t2 * ov[i];
    }
  }
  #pragma unroll
  for (int m = 0; m < 4; ++m)
    *(float4*)&Pl[w][m][lane * 4] = *(float4*)a[m];
  __syncthreads();
  #pragma unroll
  for (int e = 0; e < 4; ++e) {
    const int idx = tid + e * 256;
    const int m = idx >> 8, d = idx & 255;
    const float s = Pl[0][m][d] + Pl[1][m][d] + Pl[2][m][d] + Pl[3][m][d];
    Up[(((size_t)b * 16 + c) * 4 + m) * DMOD + d] = s;
  }
}

// ---------------- final [32,2048] partial-sum @ [1024,2]^T + bias ---------------
__global__ __launch_bounds__(256) void k_out(
    const float* __restrict__ Up, const float* __restrict__ ow,
    const float* __restrict__ ob, float* __restrict__ out) {
  const int b = blockIdx.x;
  const int tid = threadIdx.x;
  const int w = tid >> 6;
  const int lane = tid & 63;
  __shared__ float rr[8];
  float4 s = {0.f, 0.f, 0.f, 0.f};
  #pragma unroll
  for (int c = 0; c < 16; ++c) {
    const float4 u = *(const float4*)(Up + ((size_t)b * 16 + c) * 1024 + tid * 4);
    s.x += u.x; s.y += u.y; s.z += u.z; s.w += u.w;
  }
  const float4 w0 = *(const float4*)(ow + tid * 4);
  const float4 w1 = *(const float4*)(ow + 1024 + tid * 4);
  float acc0 = s.x * w0.x + s.y * w0.y + s.z * w0.z + s.w * w0.w;
  float acc1 = s.x * w1.x + s.y * w1.y + s.z * w1.z + s.w * w1.w;
  #pragma unroll
  for (int off = 32; off > 0; off >>= 1) {
    acc0 += __shfl_xor(acc0, off);
    acc1 += __shfl_xor(acc1, off);
  }
  if (lane == 0) { rr[w] = acc0; rr[4 + w] = acc1; }
  __syncthreads();
  if (tid == 0) {
    out[b * 2 + 0] = rr[0] + rr[1] + rr[2] + rr[3] + ob[0];
    out[b * 2 + 1] = rr[4] + rr[5] + rr[6] + rr[7] + ob[1];
  }
}

extern "C" void kernel_launch(void* const* d_in, const int* in_sizes, int n_in,
                              void* d_out, int out_size, void* d_ws, size_t ws_size,
                              hipStream_t stream) {
  const int* seqs     = (const int*)d_in[0];
  const int* masks    = (const int*)d_in[1];
  const int* lengths  = (const int*)d_in[2];
  const float* emb    = (const float*)d_in[5];
  const float* bias   = (const float*)d_in[6];
  const float* pe     = (const float*)d_in[7];
  const float* Wq     = (const float*)d_in[8];
  const float* Wk     = (const float*)d_in[9];
  const float* Wv     = (const float*)d_in[10];
  const float* Wfc    = (const float*)d_in[11];
  const float* ln_g   = (const float*)d_in[12];
  const float* ln_b   = (const float*)d_in[13];
  const float* out_w  = (const float*)d_in[14];
  const float* out_b  = (const float*)d_in[15];
  float* outp = (float*)d_out;

  const size_t NE = (size_t)BSZ * SLEN * DMOD;   // 4,194,304
  _Float16* q = (_Float16*)d_ws;
  _Float16* k = q + NE;
  _Float16* v = k + NE;
  _Float16* vt = v + NE;
  _Float16* x = vt + NE;
  _Float16* o = x + NE;
  _Float16* wh = o + NE;                         // 4*65536 halfs
  unsigned int* pk = (unsigned int*)(wh + 4 * 65536);
  float* Up = (float*)(pk + BSZ * SLEN * 16);    // [32][16][4][256] fp32 = 2 MB
  float* y = (float*)q;                          // alias: q,k dead after attn
  // fp16 emb table (10.24 MB) aliases q+k: dead before gemm_qkv writes them
  _Float16* embh = (_Float16*)d_ws;

  k_cast<<<2628, 256, 0, stream>>>(Wq, Wk, Wv, Wfc, emb, wh, embh);
  k_embmask<<<BSZ * SLEN / 8, 256, 0, stream>>>(seqs, lengths, embh, bias, pe, x,
                                                masks, pk);
  k_gemm_qkv<<<dim3(128, 2, 3), 256, 0, stream>>>(x, wh, q, k, v);
  k_vt<<<dim3(BSZ * NH, 8), 256, 0, stream>>>(v, vt);
  k_attn<<<BSZ * NH * (SLEN / 128), 256, 0, stream>>>(q, k, vt, pk, o);
  k_gemm_fc<<<dim3(128, 2), 256, 0, stream>>>(o, wh + 3 * 65536, y, x);
  k_lnpool<<<dim3(BSZ, 16), 256, 0, stream>>>(y, lengths, ln_g, ln_b, Up);
  k_out<<<BSZ, 256, 0, stream>>>(Up, out_w, out_b, outp);
}

// Round 9
// 217.506 us; speedup vs baseline: 1.0280x; 1.0227x over previous
//
#include <hip/hip_runtime.h>

#define BSZ 32
#define SLEN 512
#define CLEN 20
#define DMOD 256
#define NH 4
#define HDIM 64

typedef _Float16 half8 __attribute__((ext_vector_type(8)));
typedef _Float16 half4 __attribute__((ext_vector_type(4)));
typedef float float4v __attribute__((ext_vector_type(4)));

#define MFMA16(a, b, c) __builtin_amdgcn_mfma_f32_16x16x32_f16(a, b, c, 0, 0, 0)
// padded half8 index: groups of 16 half8 get stride 17 (breaks 256B-stride conflicts)
#define PG(fi) ((((fi) >> 4) * 17) + ((fi) & 15))

// ---------------- merged fp32->fp16 cast: 4 weight mats + embedding table ------
__global__ __launch_bounds__(256) void k_cast(
    const float* __restrict__ W0, const float* __restrict__ W1,
    const float* __restrict__ W2, const float* __restrict__ W3,
    const float* __restrict__ emb,
    _Float16* __restrict__ wh, _Float16* __restrict__ embh) {
  const int bid = blockIdx.x;
  const float* src;
  _Float16* dst;
  int idx;
  if (bid < 128) {
    const int z = bid >> 5;
    src = (z == 0) ? W0 : (z == 1) ? W1 : (z == 2) ? W2 : W3;
    dst = wh + (size_t)z * 65536;
    idx = ((bid & 31) * 256 + threadIdx.x) * 8;
  } else {
    src = emb;
    dst = embh;
    idx = ((bid - 128) * 256 + threadIdx.x) * 8;
  }
  float v[8];
  *(float4*)v = *(const float4*)(src + idx);
  *(float4*)(v + 4) = *(const float4*)(src + idx + 4);
  half8 h;
  #pragma unroll
  for (int i = 0; i < 8; ++i) h[i] = (_Float16)v[i];
  *(half8*)(dst + idx) = h;
}

// ---------------- fused: embedding sum + pos-enc -> fp16, AND mask bit-pack -----
__global__ __launch_bounds__(256) void k_embmask(
    const int* __restrict__ seqs, const int* __restrict__ lengths,
    const _Float16* __restrict__ embh, const float* __restrict__ bias,
    const float* __restrict__ pe, _Float16* __restrict__ x,
    const int* __restrict__ masks, unsigned int* __restrict__ pk) {
  const int row0 = blockIdx.x * 8;
  const int sub = threadIdx.x >> 5;
  const int hl = threadIdx.x & 31;
  const int row = row0 + sub;
  const int b = row >> 9, s = row & 511;
  __shared__ int codes[8][CLEN];
  if (threadIdx.x < 8 * CLEN)
    codes[threadIdx.x / CLEN][threadIdx.x % CLEN] = seqs[row0 * CLEN + threadIdx.x];
  __syncthreads();
  const int pos = (s < lengths[b]) ? (s + 1) : 0;
  const int d = hl * 8;
  float acc[8];
  *(float4*)acc = *(const float4*)(bias + d);
  *(float4*)(acc + 4) = *(const float4*)(bias + d + 4);
  const float4 pv0 = *(const float4*)(pe + (size_t)pos * DMOD + d);
  const float4 pv1 = *(const float4*)(pe + (size_t)pos * DMOD + d + 4);
  acc[0] += pv0.x; acc[1] += pv0.y; acc[2] += pv0.z; acc[3] += pv0.w;
  acc[4] += pv1.x; acc[5] += pv1.y; acc[6] += pv1.z; acc[7] += pv1.w;
  #pragma unroll
  for (int c = 0; c < CLEN; ++c) {
    const half8 ev = *(const half8*)(embh + (size_t)codes[sub][c] * DMOD + d);
    #pragma unroll
    for (int i = 0; i < 8; ++i) acc[i] += (float)ev[i];
  }
  half8 hv;
  #pragma unroll
  for (int i = 0; i < 8; ++i) hv[i] = (_Float16)acc[i];
  *(half8*)(x + (size_t)row * DMOD + d) = hv;
  // ---- phase 2: mask bit-pack ----
  const int wv = threadIdx.x >> 6;
  const int lane = threadIdx.x & 63;
  #pragma unroll
  for (int p = 0; p < 16; ++p) {
    const int it = wv + p * 4;
    const int r = row0 + (it >> 3);
    const int chunk = it & 7;
    const int m = masks[(size_t)r * SLEN + chunk * 64 + lane];
    const unsigned long long bal = __ballot(m != 0);
    if (lane == 0) {
      pk[(size_t)r * 16 + chunk * 2]     = (unsigned int)bal;
      pk[(size_t)r * 16 + chunk * 2 + 1] = (unsigned int)(bal >> 32);
    }
  }
}

// ---------------- QKV GEMM: fp16 MFMA, prefetch, vectorized epilogue ------------
__global__ __launch_bounds__(256) void k_gemm_qkv(
    const _Float16* __restrict__ A, const _Float16* __restrict__ Wb,
    _Float16* __restrict__ q, _Float16* __restrict__ k, _Float16* __restrict__ v) {
  const int z = blockIdx.z;
  _Float16* Cb = (z == 0) ? q : (z == 1) ? k : v;
  const _Float16* w_ = Wb + (size_t)z * 65536;
  const int m0 = blockIdx.x * 128;
  const int n0 = blockIdx.y * 128;
  const int tid = threadIdx.x;
  const int lane = tid & 63;
  const int w = tid >> 6;
  const int wm = (w >> 1) * 4;
  const int wn = (w & 1) * 4;
  __shared__ _Float16 smem[8704];
  half8* As = (half8*)(smem);
  half8* Ws = (half8*)(smem + 4096);
  float4v acc[4][4];
  #pragma unroll
  for (int i = 0; i < 4; ++i)
    #pragma unroll
    for (int j = 0; j < 4; ++j)
      acc[i][j] = (float4v){0.f, 0.f, 0.f, 0.f};
  int li_[2]; size_t ga_[2], gw_[2];
  #pragma unroll
  for (int p = 0; p < 2; ++p) {
    const int c = tid + p * 256;
    const int r = c & 127, qd = c >> 7;
    li_[p] = (r >> 4) * 64 + qd * 16 + (r & 15);
    ga_[p] = (size_t)(m0 + r) * DMOD + qd * 8;
    gw_[p] = (size_t)(n0 + r) * DMOD + qd * 8;
  }
  half8 pa[2], pw[2];
  #pragma unroll
  for (int p = 0; p < 2; ++p) {
    pa[p] = *(const half8*)(A + ga_[p]);
    pw[p] = *(const half8*)(w_ + gw_[p]);
  }
  for (int k0 = 0; k0 < DMOD; k0 += 32) {
    #pragma unroll
    for (int p = 0; p < 2; ++p) {
      As[li_[p]] = pa[p];
      Ws[li_[p]] = pw[p];
    }
    __syncthreads();
    if (k0 + 32 < DMOD) {
      #pragma unroll
      for (int p = 0; p < 2; ++p) {
        pa[p] = *(const half8*)(A + ga_[p] + k0 + 32);
        pw[p] = *(const half8*)(w_ + gw_[p] + k0 + 32);
      }
    }
    half8 af[4], wf[4];
    #pragma unroll
    for (int i = 0; i < 4; ++i) {
      af[i] = As[(wm + i) * 64 + lane];
      wf[i] = Ws[(wn + i) * 64 + lane];
    }
    #pragma unroll
    for (int i = 0; i < 4; ++i)
      #pragma unroll
      for (int j = 0; j < 4; ++j)
        acc[i][j] = MFMA16(af[i], wf[j], acc[i][j]);
    __syncthreads();
  }
  const int cr = (lane >> 4) * 4;
  const int cc = lane & 15;
  _Float16* Eh = smem;
  #pragma unroll
  for (int ip = 0; ip < 4; ++ip) {
    #pragma unroll
    for (int j = 0; j < 4; ++j) {
      const int col = (wn + j) * 16 + cc;
      #pragma unroll
      for (int r = 0; r < 4; ++r)
        Eh[((w >> 1) * 16 + cr + r) * 136 + col] = (_Float16)acc[ip][j][r];
    }
    __syncthreads();
    #pragma unroll
    for (int e = 0; e < 2; ++e) {
      const int idx = tid + e * 256;
      const int lr = idx >> 4;
      const int cg = idx & 15;
      const int gr = m0 + (lr >> 4) * 64 + ip * 16 + (lr & 15);
      *(half8*)(Cb + (size_t)gr * DMOD + n0 + cg * 8) =
          *(const half8*)&Eh[lr * 136 + cg * 8];
    }
    __syncthreads();
  }
}

// ---------------- per-bh transpose: v[bh][s][d] -> vt[bh][d][s] -----------------
__global__ __launch_bounds__(256) void k_vt(
    const _Float16* __restrict__ v, _Float16* __restrict__ vt) {
  const int bh = blockIdx.x;
  const size_t off = (size_t)bh * 32768;
  __shared__ _Float16 Th[64][66];
  const int tid = threadIdx.x;
  const int sc = blockIdx.y * 64;
  #pragma unroll
  for (int p = 0; p < 2; ++p) {
    const int lin = tid + p * 256;
    const int r = lin >> 3, g = lin & 7;
    *(half8*)&Th[r][g * 8] = *(const half8*)(v + off + (size_t)(sc + r) * 64 + g * 8);
  }
  __syncthreads();
  #pragma unroll
  for (int p = 0; p < 2; ++p) {
    const int lin = tid + p * 256;
    const int d = lin >> 3, sg = lin & 7;
    half8 hv;
    #pragma unroll
    for (int j = 0; j < 8; ++j) hv[j] = Th[sg * 8 + j][d];
    *(half8*)(vt + off + (size_t)d * 512 + sc + sg * 8) = hv;
  }
}

// ---------------- fused FC GEMM + layer norm + pooling --------------------------
// BM=64 x BN=256 tile (full row width) -> per-row LN in epilogue; no Y buffer.
// grid 256 blocks = 1/CU (same as old fc). Verified GEMM core with wm=0, wn=4w;
// LN/pool math copied verbatim from verified k_lnpool. Writes Up[32][8][4][256].
__global__ __launch_bounds__(256) void k_fcln(
    const _Float16* __restrict__ A, const _Float16* __restrict__ w_,
    const _Float16* __restrict__ res, const int* __restrict__ lengths,
    const float* __restrict__ g, const float* __restrict__ bb,
    float* __restrict__ Up) {
  const int m0 = blockIdx.x * 64;
  const int b = m0 >> 9;
  const int s0 = m0 & 511;
  const int tid = threadIdx.x;
  const int lane = tid & 63;
  const int w = tid >> 6;
  __shared__ half8 As[256], Ws[1024];           // 4 KB + 16 KB
  __shared__ float Rs[4][64], Rq[4][64];        // per-wave row partials
  __shared__ float Fmu[64], Fiv[64];
  float4v acc[4][4];
  #pragma unroll
  for (int i = 0; i < 4; ++i)
    #pragma unroll
    for (int j = 0; j < 4; ++j)
      acc[i][j] = (float4v){0.f, 0.f, 0.f, 0.f};
  // staging addresses: A 64 rows x 32k (1/thread), W 256 cols x 32k (4/thread)
  const int ra = tid & 63, qa = tid >> 6;
  const int li_a = (ra >> 4) * 64 + qa * 16 + (ra & 15);
  const size_t ga_ = (size_t)(m0 + ra) * DMOD + qa * 8;
  int li_w[4]; size_t gw_[4];
  #pragma unroll
  for (int p = 0; p < 4; ++p) {
    const int c = tid + p * 256;
    const int rw = c & 255, qw = c >> 8;
    li_w[p] = (rw >> 4) * 64 + qw * 16 + (rw & 15);
    gw_[p] = (size_t)rw * DMOD + qw * 8;
  }
  half8 pa = *(const half8*)(A + ga_);
  half8 pw[4];
  #pragma unroll
  for (int p = 0; p < 4; ++p) pw[p] = *(const half8*)(w_ + gw_[p]);
  for (int k0 = 0; k0 < DMOD; k0 += 32) {
    As[li_a] = pa;
    #pragma unroll
    for (int p = 0; p < 4; ++p) Ws[li_w[p]] = pw[p];
    __syncthreads();
    if (k0 + 32 < DMOD) {
      pa = *(const half8*)(A + ga_ + k0 + 32);
      #pragma unroll
      for (int p = 0; p < 4; ++p) pw[p] = *(const half8*)(w_ + gw_[p] + k0 + 32);
    }
    half8 af[4], wf[4];
    #pragma unroll
    for (int i = 0; i < 4; ++i) {
      af[i] = As[i * 64 + lane];                // wm = 0: all waves share rows
      wf[i] = Ws[(w * 4 + i) * 64 + lane];      // wn = 4w
    }
    #pragma unroll
    for (int i = 0; i < 4; ++i)
      #pragma unroll
      for (int j = 0; j < 4; ++j)
        acc[i][j] = MFMA16(af[i], wf[j], acc[i][j]);
    __syncthreads();
  }
  const int cr = (lane >> 4) * 4;               // quad*4
  const int cc = lane & 15;
  const int l15 = cc;
  // add residual (in place): row_l = i*16+cr+rr, col = (4w+j)*16+cc
  #pragma unroll
  for (int i = 0; i < 4; ++i)
    #pragma unroll
    for (int j = 0; j < 4; ++j) {
      const int col = (w * 4 + j) * 16 + cc;
      #pragma unroll
      for (int r = 0; r < 4; ++r)
        acc[i][j][r] += (float)res[(size_t)(m0 + i * 16 + cr + r) * DMOD + col];
    }
  // row sums (sum + sqsum over 256 cols): j-local, then cc-butterfly, then waves
  float S[4][4], Q2[4][4];
  #pragma unroll
  for (int i = 0; i < 4; ++i)
    #pragma unroll
    for (int r = 0; r < 4; ++r) {
      float s = 0.f, q2 = 0.f;
      #pragma unroll
      for (int j = 0; j < 4; ++j) {
        const float v = acc[i][j][r];
        s += v; q2 += v * v;
      }
      #pragma unroll
      for (int off = 1; off <= 8; off <<= 1) {
        s += __shfl_xor(s, off);
        q2 += __shfl_xor(q2, off);
      }
      S[i][r] = s; Q2[i][r] = q2;
    }
  if (l15 == 0) {
    #pragma unroll
    for (int i = 0; i < 4; ++i)
      #pragma unroll
      for (int r = 0; r < 4; ++r) {
        Rs[w][i * 16 + cr + r] = S[i][r];
        Rq[w][i * 16 + cr + r] = Q2[i][r];
      }
  }
  __syncthreads();
  if (tid < 64) {
    const float s = Rs[0][tid] + Rs[1][tid] + Rs[2][tid] + Rs[3][tid];
    const float q2 = Rq[0][tid] + Rq[1][tid] + Rq[2][tid] + Rq[3][tid];
    const float mu = s * (1.0f / DMOD);
    Fmu[tid] = mu;
    Fiv[tid] = rsqrtf(q2 * (1.0f / DMOD) - mu * mu + 1e-5f);
  }
  __syncthreads();
  // LN + validity + triangular pooling (formulas verbatim from k_lnpool)
  const int len = lengths[b];
  const float inv4 = 4.0f / (float)len;
  float gl[4], bl[4];
  #pragma unroll
  for (int j = 0; j < 4; ++j) {
    const int col = (w * 4 + j) * 16 + cc;
    gl[j] = g[col]; bl[j] = bb[col];
  }
  float pool[4][4] = {};                        // [bin][j]
  #pragma unroll
  for (int i = 0; i < 4; ++i)
    #pragma unroll
    for (int r = 0; r < 4; ++r) {
      const int row_l = i * 16 + cr + r;
      const int sg = s0 + row_l;
      const bool valid = sg < len;
      const float mu = Fmu[row_l], iv = Fiv[row_l];
      const float sv = (float)(sg + 1) * inv4;
      float t2[4];
      #pragma unroll
      for (int m = 0; m < 4; ++m) {
        const float tm = 1.0f - fabsf(sv - (float)(m + 1)) * 0.25f;
        t2[m] = tm * tm;
      }
      #pragma unroll
      for (int j = 0; j < 4; ++j) {
        const float ov = valid ? (acc[i][j][r] - mu) * iv * gl[j] + bl[j] : 0.f;
        #pragma unroll
        for (int m = 0; m < 4; ++m) pool[m][j] += t2[m] * ov;
      }
    }
  // reduce pool over the 4 quads (rows partition across quads)
  #pragma unroll
  for (int m = 0; m < 4; ++m)
    #pragma unroll
    for (int j = 0; j < 4; ++j) {
      pool[m][j] += __shfl_xor(pool[m][j], 16);
      pool[m][j] += __shfl_xor(pool[m][j], 32);
    }
  const int sc = (m0 >> 6) & 7;
  if ((lane >> 4) == 0) {
    #pragma unroll
    for (int m = 0; m < 4; ++m)
      #pragma unroll
      for (int j = 0; j < 4; ++j)
        Up[(((size_t)b * 8 + sc) * 4 + m) * DMOD + (w * 4 + j) * 16 + cc] =
            pool[m][j];
  }
}

// ---------------- MFMA attention per (bh, q-tile of 128), fp16 ------------------
__global__ __launch_bounds__(256, 2) void k_attn(
    const _Float16* __restrict__ q_, const _Float16* __restrict__ k_,
    const _Float16* __restrict__ vt, const unsigned int* __restrict__ pk,
    _Float16* __restrict__ o) {
  const int L = blockIdx.x;
  const int bh = (L & 7) * 16 + ((L >> 3) & 15);
  const int q0 = (L >> 7) * 128;
  const size_t bhoff = (size_t)bh * 32768;
  __shared__ half8 QP[1088];
  __shared__ half8 Ks[544], Vs[544];
  __shared__ unsigned long long Ms64[128];
  __shared__ float Ps[4][128];
  __shared__ float lsum[128];
  const int tid = threadIdx.x;
  const int w = tid >> 6;
  const int lane = tid & 63;
  const int l15 = lane & 15;
  const int quad = lane >> 4;
  #pragma unroll
  for (int p = 0; p < 4; ++p) {
    const int lin = tid + p * 256;
    const int r = lin >> 3, g = lin & 7;
    const int fi = (r >> 4) * 128 + g * 16 + (r & 15);
    QP[PG(fi)] = *(const half8*)(q_ + bhoff + (size_t)(q0 + r) * 64 + g * 8);
  }
  __syncthreads();
  half8 qf[8][2];
  #pragma unroll
  for (int ns = 0; ns < 8; ++ns) {
    const int gq = ns * 8 + quad;
    qf[ns][0] = QP[gq * 17 + l15];
    qf[ns][1] = QP[(gq + 4) * 17 + l15];
  }
  float4v oacc[8];
  float lsw[8] = {0.f, 0.f, 0.f, 0.f, 0.f, 0.f, 0.f, 0.f};
  #pragma unroll
  for (int ns = 0; ns < 8; ++ns) oacc[ns] = (float4v){0.f, 0.f, 0.f, 0.f};
  for (int kc = 0; kc < SLEN; kc += 64) {
    __syncthreads();
    #pragma unroll
    for (int p = 0; p < 2; ++p) {
      const int lin = tid + p * 256;
      const int r = lin >> 3, g = lin & 7;
      const int fi = PG((r >> 4) * 128 + g * 16 + (r & 15));
      Ks[fi] = *(const half8*)(k_ + bhoff + (size_t)(kc + r) * 64 + g * 8);
      Vs[fi] = *(const half8*)(vt + bhoff + (size_t)r * 512 + kc + g * 8);
    }
    ((unsigned int*)Ms64)[tid] =
        pk[((size_t)((bh >> 2) << 9) + q0 + (tid >> 1)) * 16 + (kc >> 5) + (tid & 1)];
    __syncthreads();
    const int ga0 = (w * 8 + quad) * 17 + l15;
    const int ga1 = (w * 8 + quad + 4) * 17 + l15;
    const half8 ah0 = Ks[ga0], ah1 = Ks[ga1];
    #pragma unroll
    for (int ns = 0; ns < 8; ++ns) {
      float4v s = (float4v){0.f, 0.f, 0.f, 0.f};
      s = MFMA16(ah0, qf[ns][0], s);
      s = MFMA16(ah1, qf[ns][1], s);
      const int q = ns * 16 + l15;
      const unsigned long long mrow = Ms64[q];
      const unsigned mbits = (unsigned)(mrow >> (w * 16 + quad * 4)) & 15u;
      half4 h4;
      #pragma unroll
      for (int r = 0; r < 4; ++r) {
        const float pe = ((mbits >> r) & 1u) ? __expf(s[r] * 0.125f) : 0.f;
        h4[r] = (_Float16)pe;
        lsw[ns] += pe;
      }
      const int hb = ((ns * 8 + w * 2 + (quad >> 1)) * 17 + l15) * 8 + (quad & 1) * 4;
      *(half4*)((_Float16*)QP + hb) = h4;
    }
    __syncthreads();
    const half8 vh0 = Vs[ga0], vh1 = Vs[ga1];
    #pragma unroll
    for (int ns = 0; ns < 8; ++ns) {
      const int pb0 = (ns * 8 + quad) * 17 + l15;
      const int pb1 = (ns * 8 + quad + 4) * 17 + l15;
      oacc[ns] = MFMA16(vh0, QP[pb0], oacc[ns]);
      oacc[ns] = MFMA16(vh1, QP[pb1], oacc[ns]);
    }
  }
  #pragma unroll
  for (int ns = 0; ns < 8; ++ns) {
    lsw[ns] += __shfl_xor(lsw[ns], 16);
    lsw[ns] += __shfl_xor(lsw[ns], 32);
  }
  __syncthreads();
  if (quad == 0) {
    #pragma unroll
    for (int ns = 0; ns < 8; ++ns) Ps[w][ns * 16 + l15] = lsw[ns];
  }
  __syncthreads();
  if (tid < 128) lsum[tid] = Ps[0][tid] + Ps[1][tid] + Ps[2][tid] + Ps[3][tid];
  __syncthreads();
  const int b = bh >> 2, h = bh & 3;
  _Float16* Ot = (_Float16*)QP;
  #pragma unroll
  for (int ns = 0; ns < 8; ++ns) {
    const int q = ns * 16 + l15;
    const float inv = 1.0f / lsum[q];
    half4 h4;
    #pragma unroll
    for (int r = 0; r < 4; ++r) h4[r] = (_Float16)(oacc[ns][r] * inv);
    *(half4*)&Ot[q * 68 + w * 16 + quad * 4] = h4;
  }
  __syncthreads();
  #pragma unroll
  for (int e = 0; e < 4; ++e) {
    const int idx = tid + e * 256;
    const int qq = idx >> 3, g = idx & 7;
    *(half8*)(o + ((size_t)(b * SLEN + q0 + qq)) * DMOD + h * HDIM + g * 8) =
        *(const half8*)&Ot[qq * 68 + g * 8];
  }
}

// ---------------- final [32,1024] @ [1024,2]^T + bias (8 s-chunks) --------------
__global__ __launch_bounds__(256) void k_out(
    const float* __restrict__ Up, const float* __restrict__ ow,
    const float* __restrict__ ob, float* __restrict__ out) {
  const int b = blockIdx.x;
  const int tid = threadIdx.x;
  const int w = tid >> 6;
  const int lane = tid & 63;
  __shared__ float rr[8];
  float4 s = {0.f, 0.f, 0.f, 0.f};
  #pragma unroll
  for (int c = 0; c < 8; ++c) {
    const float4 u = *(const float4*)(Up + ((size_t)b * 8 + c) * 1024 + tid * 4);
    s.x += u.x; s.y += u.y; s.z += u.z; s.w += u.w;
  }
  const float4 w0 = *(const float4*)(ow + tid * 4);
  const float4 w1 = *(const float4*)(ow + 1024 + tid * 4);
  float acc0 = s.x * w0.x + s.y * w0.y + s.z * w0.z + s.w * w0.w;
  float acc1 = s.x * w1.x + s.y * w1.y + s.z * w1.z + s.w * w1.w;
  #pragma unroll
  for (int off = 32; off > 0; off >>= 1) {
    acc0 += __shfl_xor(acc0, off);
    acc1 += __shfl_xor(acc1, off);
  }
  if (lane == 0) { rr[w] = acc0; rr[4 + w] = acc1; }
  __syncthreads();
  if (tid == 0) {
    out[b * 2 + 0] = rr[0] + rr[1] + rr[2] + rr[3] + ob[0];
    out[b * 2 + 1] = rr[4] + rr[5] + rr[6] + rr[7] + ob[1];
  }
}

extern "C" void kernel_launch(void* const* d_in, const int* in_sizes, int n_in,
                              void* d_out, int out_size, void* d_ws, size_t ws_size,
                              hipStream_t stream) {
  const int* seqs     = (const int*)d_in[0];
  const int* masks    = (const int*)d_in[1];
  const int* lengths  = (const int*)d_in[2];
  const float* emb    = (const float*)d_in[5];
  const float* bias   = (const float*)d_in[6];
  const float* pe     = (const float*)d_in[7];
  const float* Wq     = (const float*)d_in[8];
  const float* Wk     = (const float*)d_in[9];
  const float* Wv     = (const float*)d_in[10];
  const float* Wfc    = (const float*)d_in[11];
  const float* ln_g   = (const float*)d_in[12];
  const float* ln_b   = (const float*)d_in[13];
  const float* out_w  = (const float*)d_in[14];
  const float* out_b  = (const float*)d_in[15];
  float* outp = (float*)d_out;

  const size_t NE = (size_t)BSZ * SLEN * DMOD;   // 4,194,304
  _Float16* q = (_Float16*)d_ws;
  _Float16* k = q + NE;
  _Float16* v = k + NE;
  _Float16* vt = v + NE;
  _Float16* x = vt + NE;
  _Float16* o = x + NE;
  _Float16* wh = o + NE;                         // 4*65536 halfs
  unsigned int* pk = (unsigned int*)(wh + 4 * 65536);
  float* Up = (float*)(pk + BSZ * SLEN * 16);    // [32][8][4][256] fp32 = 1 MB
  // fp16 emb table (10.24 MB) aliases q+k: dead before gemm_qkv writes them
  _Float16* embh = (_Float16*)d_ws;

  k_cast<<<2628, 256, 0, stream>>>(Wq, Wk, Wv, Wfc, emb, wh, embh);
  k_embmask<<<BSZ * SLEN / 8, 256, 0, stream>>>(seqs, lengths, embh, bias, pe, x,
                                                masks, pk);
  k_gemm_qkv<<<dim3(128, 2, 3), 256, 0, stream>>>(x, wh, q, k, v);
  k_vt<<<dim3(BSZ * NH, 8), 256, 0, stream>>>(v, vt);
  k_attn<<<BSZ * NH * (SLEN / 128), 256, 0, stream>>>(q, k, vt, pk, o);
  k_fcln<<<256, 256, 0, stream>>>(o, wh + 3 * 65536, x, lengths, ln_g, ln_b, Up);
  k_out<<<BSZ, 256, 0, stream>>>(Up, out_w, out_b, outp);
}

// Round 11
// 210.372 us; speedup vs baseline: 1.0629x; 1.0339x over previous
//
#include <hip/hip_runtime.h>

#define BSZ 32
#define SLEN 512
#define CLEN 20
#define DMOD 256
#define NH 4
#define HDIM 64

typedef _Float16 half8 __attribute__((ext_vector_type(8)));
typedef _Float16 half4 __attribute__((ext_vector_type(4)));
typedef float float4v __attribute__((ext_vector_type(4)));

#define MFMA16(a, b, c) __builtin_amdgcn_mfma_f32_16x16x32_f16(a, b, c, 0, 0, 0)
// padded half8 index: groups of 16 half8 get stride 17 (breaks 256B-stride conflicts)
#define PG(fi) ((((fi) >> 4) * 17) + ((fi) & 15))

// ---------------- merged fp32->fp16 cast: 4 weight mats + embedding table ------
__global__ __launch_bounds__(256) void k_cast(
    const float* __restrict__ W0, const float* __restrict__ W1,
    const float* __restrict__ W2, const float* __restrict__ W3,
    const float* __restrict__ emb,
    _Float16* __restrict__ wh, _Float16* __restrict__ embh) {
  const int bid = blockIdx.x;
  const float* src;
  _Float16* dst;
  int idx;
  if (bid < 128) {
    const int z = bid >> 5;
    src = (z == 0) ? W0 : (z == 1) ? W1 : (z == 2) ? W2 : W3;
    dst = wh + (size_t)z * 65536;
    idx = ((bid & 31) * 256 + threadIdx.x) * 8;
  } else {
    src = emb;
    dst = embh;
    idx = ((bid - 128) * 256 + threadIdx.x) * 8;
  }
  float v[8];
  *(float4*)v = *(const float4*)(src + idx);
  *(float4*)(v + 4) = *(const float4*)(src + idx + 4);
  half8 h;
  #pragma unroll
  for (int i = 0; i < 8; ++i) h[i] = (_Float16)v[i];
  *(half8*)(dst + idx) = h;
}

// ---------------- fused: embedding sum + pos-enc -> fp16, AND mask bit-pack -----
__global__ __launch_bounds__(256) void k_embmask(
    const int* __restrict__ seqs, const int* __restrict__ lengths,
    const _Float16* __restrict__ embh, const float* __restrict__ bias,
    const float* __restrict__ pe, _Float16* __restrict__ x,
    const int* __restrict__ masks, unsigned int* __restrict__ pk) {
  const int row0 = blockIdx.x * 8;
  const int sub = threadIdx.x >> 5;
  const int hl = threadIdx.x & 31;
  const int row = row0 + sub;
  const int b = row >> 9, s = row & 511;
  __shared__ int codes[8][CLEN];
  if (threadIdx.x < 8 * CLEN)
    codes[threadIdx.x / CLEN][threadIdx.x % CLEN] = seqs[row0 * CLEN + threadIdx.x];
  __syncthreads();
  const int pos = (s < lengths[b]) ? (s + 1) : 0;
  const int d = hl * 8;
  float acc[8];
  *(float4*)acc = *(const float4*)(bias + d);
  *(float4*)(acc + 4) = *(const float4*)(bias + d + 4);
  const float4 pv0 = *(const float4*)(pe + (size_t)pos * DMOD + d);
  const float4 pv1 = *(const float4*)(pe + (size_t)pos * DMOD + d + 4);
  acc[0] += pv0.x; acc[1] += pv0.y; acc[2] += pv0.z; acc[3] += pv0.w;
  acc[4] += pv1.x; acc[5] += pv1.y; acc[6] += pv1.z; acc[7] += pv1.w;
  #pragma unroll
  for (int c = 0; c < CLEN; ++c) {
    const half8 ev = *(const half8*)(embh + (size_t)codes[sub][c] * DMOD + d);
    #pragma unroll
    for (int i = 0; i < 8; ++i) acc[i] += (float)ev[i];
  }
  half8 hv;
  #pragma unroll
  for (int i = 0; i < 8; ++i) hv[i] = (_Float16)acc[i];
  *(half8*)(x + (size_t)row * DMOD + d) = hv;
  // ---- phase 2: mask bit-pack ----
  const int wv = threadIdx.x >> 6;
  const int lane = threadIdx.x & 63;
  #pragma unroll
  for (int p = 0; p < 16; ++p) {
    const int it = wv + p * 4;
    const int r = row0 + (it >> 3);
    const int chunk = it & 7;
    const int m = masks[(size_t)r * SLEN + chunk * 64 + lane];
    const unsigned long long bal = __ballot(m != 0);
    if (lane == 0) {
      pk[(size_t)r * 16 + chunk * 2]     = (unsigned int)bal;
      pk[(size_t)r * 16 + chunk * 2 + 1] = (unsigned int)(bal >> 32);
    }
  }
}

// ---------------- QKV GEMM: fp16 MFMA, prefetch, vectorized epilogue ------------
__global__ __launch_bounds__(256) void k_gemm_qkv(
    const _Float16* __restrict__ A, const _Float16* __restrict__ Wb,
    _Float16* __restrict__ q, _Float16* __restrict__ k, _Float16* __restrict__ v) {
  const int z = blockIdx.z;
  _Float16* Cb = (z == 0) ? q : (z == 1) ? k : v;
  const _Float16* w_ = Wb + (size_t)z * 65536;
  const int m0 = blockIdx.x * 128;
  const int n0 = blockIdx.y * 128;
  const int tid = threadIdx.x;
  const int lane = tid & 63;
  const int w = tid >> 6;
  const int wm = (w >> 1) * 4;
  const int wn = (w & 1) * 4;
  __shared__ _Float16 smem[8704];
  half8* As = (half8*)(smem);
  half8* Ws = (half8*)(smem + 4096);
  float4v acc[4][4];
  #pragma unroll
  for (int i = 0; i < 4; ++i)
    #pragma unroll
    for (int j = 0; j < 4; ++j)
      acc[i][j] = (float4v){0.f, 0.f, 0.f, 0.f};
  int li_[2]; size_t ga_[2], gw_[2];
  #pragma unroll
  for (int p = 0; p < 2; ++p) {
    const int c = tid + p * 256;
    const int r = c & 127, qd = c >> 7;
    li_[p] = (r >> 4) * 64 + qd * 16 + (r & 15);
    ga_[p] = (size_t)(m0 + r) * DMOD + qd * 8;
    gw_[p] = (size_t)(n0 + r) * DMOD + qd * 8;
  }
  half8 pa[2], pw[2];
  #pragma unroll
  for (int p = 0; p < 2; ++p) {
    pa[p] = *(const half8*)(A + ga_[p]);
    pw[p] = *(const half8*)(w_ + gw_[p]);
  }
  for (int k0 = 0; k0 < DMOD; k0 += 32) {
    #pragma unroll
    for (int p = 0; p < 2; ++p) {
      As[li_[p]] = pa[p];
      Ws[li_[p]] = pw[p];
    }
    __syncthreads();
    if (k0 + 32 < DMOD) {
      #pragma unroll
      for (int p = 0; p < 2; ++p) {
        pa[p] = *(const half8*)(A + ga_[p] + k0 + 32);
        pw[p] = *(const half8*)(w_ + gw_[p] + k0 + 32);
      }
    }
    half8 af[4], wf[4];
    #pragma unroll
    for (int i = 0; i < 4; ++i) {
      af[i] = As[(wm + i) * 64 + lane];
      wf[i] = Ws[(wn + i) * 64 + lane];
    }
    #pragma unroll
    for (int i = 0; i < 4; ++i)
      #pragma unroll
      for (int j = 0; j < 4; ++j)
        acc[i][j] = MFMA16(af[i], wf[j], acc[i][j]);
    __syncthreads();
  }
  const int cr = (lane >> 4) * 4;
  const int cc = lane & 15;
  _Float16* Eh = smem;
  #pragma unroll
  for (int ip = 0; ip < 4; ++ip) {
    #pragma unroll
    for (int j = 0; j < 4; ++j) {
      const int col = (wn + j) * 16 + cc;
      #pragma unroll
      for (int r = 0; r < 4; ++r)
        Eh[((w >> 1) * 16 + cr + r) * 136 + col] = (_Float16)acc[ip][j][r];
    }
    __syncthreads();
    #pragma unroll
    for (int e = 0; e < 2; ++e) {
      const int idx = tid + e * 256;
      const int lr = idx >> 4;
      const int cg = idx & 15;
      const int gr = m0 + (lr >> 4) * 64 + ip * 16 + (lr & 15);
      *(half8*)(Cb + (size_t)gr * DMOD + n0 + cg * 8) =
          *(const half8*)&Eh[lr * 136 + cg * 8];
    }
    __syncthreads();
  }
}

// ---------------- per-bh transpose: v[bh][s][d] -> vt[bh][d][s] -----------------
__global__ __launch_bounds__(256) void k_vt(
    const _Float16* __restrict__ v, _Float16* __restrict__ vt) {
  const int bh = blockIdx.x;
  const size_t off = (size_t)bh * 32768;
  __shared__ _Float16 Th[64][66];
  const int tid = threadIdx.x;
  const int sc = blockIdx.y * 64;
  #pragma unroll
  for (int p = 0; p < 2; ++p) {
    const int lin = tid + p * 256;
    const int r = lin >> 3, g = lin & 7;
    *(half8*)&Th[r][g * 8] = *(const half8*)(v + off + (size_t)(sc + r) * 64 + g * 8);
  }
  __syncthreads();
  #pragma unroll
  for (int p = 0; p < 2; ++p) {
    const int lin = tid + p * 256;
    const int d = lin >> 3, sg = lin & 7;
    half8 hv;
    #pragma unroll
    for (int j = 0; j < 8; ++j) hv[j] = Th[sg * 8 + j][d];
    *(half8*)(vt + off + (size_t)d * 512 + sc + sg * 8) = hv;
  }
}

// ---------------- fused FC GEMM + layer norm + pooling --------------------------
__global__ __launch_bounds__(256) void k_fcln(
    const _Float16* __restrict__ A, const _Float16* __restrict__ w_,
    const _Float16* __restrict__ res, const int* __restrict__ lengths,
    const float* __restrict__ g, const float* __restrict__ bb,
    float* __restrict__ Up) {
  const int m0 = blockIdx.x * 64;
  const int b = m0 >> 9;
  const int s0 = m0 & 511;
  const int tid = threadIdx.x;
  const int lane = tid & 63;
  const int w = tid >> 6;
  __shared__ half8 As[256], Ws[1024];
  __shared__ float Rs[4][64], Rq[4][64];
  __shared__ float Fmu[64], Fiv[64];
  float4v acc[4][4];
  #pragma unroll
  for (int i = 0; i < 4; ++i)
    #pragma unroll
    for (int j = 0; j < 4; ++j)
      acc[i][j] = (float4v){0.f, 0.f, 0.f, 0.f};
  const int ra = tid & 63, qa = tid >> 6;
  const int li_a = (ra >> 4) * 64 + qa * 16 + (ra & 15);
  const size_t ga_ = (size_t)(m0 + ra) * DMOD + qa * 8;
  int li_w[4]; size_t gw_[4];
  #pragma unroll
  for (int p = 0; p < 4; ++p) {
    const int c = tid + p * 256;
    const int rw = c & 255, qw = c >> 8;
    li_w[p] = (rw >> 4) * 64 + qw * 16 + (rw & 15);
    gw_[p] = (size_t)rw * DMOD + qw * 8;
  }
  half8 pa = *(const half8*)(A + ga_);
  half8 pw[4];
  #pragma unroll
  for (int p = 0; p < 4; ++p) pw[p] = *(const half8*)(w_ + gw_[p]);
  for (int k0 = 0; k0 < DMOD; k0 += 32) {
    As[li_a] = pa;
    #pragma unroll
    for (int p = 0; p < 4; ++p) Ws[li_w[p]] = pw[p];
    __syncthreads();
    if (k0 + 32 < DMOD) {
      pa = *(const half8*)(A + ga_ + k0 + 32);
      #pragma unroll
      for (int p = 0; p < 4; ++p) pw[p] = *(const half8*)(w_ + gw_[p] + k0 + 32);
    }
    half8 af[4], wf[4];
    #pragma unroll
    for (int i = 0; i < 4; ++i) {
      af[i] = As[i * 64 + lane];
      wf[i] = Ws[(w * 4 + i) * 64 + lane];
    }
    #pragma unroll
    for (int i = 0; i < 4; ++i)
      #pragma unroll
      for (int j = 0; j < 4; ++j)
        acc[i][j] = MFMA16(af[i], wf[j], acc[i][j]);
    __syncthreads();
  }
  const int cr = (lane >> 4) * 4;
  const int cc = lane & 15;
  const int l15 = cc;
  #pragma unroll
  for (int i = 0; i < 4; ++i)
    #pragma unroll
    for (int j = 0; j < 4; ++j) {
      const int col = (w * 4 + j) * 16 + cc;
      #pragma unroll
      for (int r = 0; r < 4; ++r)
        acc[i][j][r] += (float)res[(size_t)(m0 + i * 16 + cr + r) * DMOD + col];
    }
  float S[4][4], Q2[4][4];
  #pragma unroll
  for (int i = 0; i < 4; ++i)
    #pragma unroll
    for (int r = 0; r < 4; ++r) {
      float s = 0.f, q2 = 0.f;
      #pragma unroll
      for (int j = 0; j < 4; ++j) {
        const float v = acc[i][j][r];
        s += v; q2 += v * v;
      }
      #pragma unroll
      for (int off = 1; off <= 8; off <<= 1) {
        s += __shfl_xor(s, off);
        q2 += __shfl_xor(q2, off);
      }
      S[i][r] = s; Q2[i][r] = q2;
    }
  if (l15 == 0) {
    #pragma unroll
    for (int i = 0; i < 4; ++i)
      #pragma unroll
      for (int r = 0; r < 4; ++r) {
        Rs[w][i * 16 + cr + r] = S[i][r];
        Rq[w][i * 16 + cr + r] = Q2[i][r];
      }
  }
  __syncthreads();
  if (tid < 64) {
    const float s = Rs[0][tid] + Rs[1][tid] + Rs[2][tid] + Rs[3][tid];
    const float q2 = Rq[0][tid] + Rq[1][tid] + Rq[2][tid] + Rq[3][tid];
    const float mu = s * (1.0f / DMOD);
    Fmu[tid] = mu;
    Fiv[tid] = rsqrtf(q2 * (1.0f / DMOD) - mu * mu + 1e-5f);
  }
  __syncthreads();
  const int len = lengths[b];
  const float inv4 = 4.0f / (float)len;
  float gl[4], bl[4];
  #pragma unroll
  for (int j = 0; j < 4; ++j) {
    const int col = (w * 4 + j) * 16 + cc;
    gl[j] = g[col]; bl[j] = bb[col];
  }
  float pool[4][4] = {};
  #pragma unroll
  for (int i = 0; i < 4; ++i)
    #pragma unroll
    for (int r = 0; r < 4; ++r) {
      const int row_l = i * 16 + cr + r;
      const int sg = s0 + row_l;
      const bool valid = sg < len;
      const float mu = Fmu[row_l], iv = Fiv[row_l];
      const float sv = (float)(sg + 1) * inv4;
      float t2[4];
      #pragma unroll
      for (int m = 0; m < 4; ++m) {
        const float tm = 1.0f - fabsf(sv - (float)(m + 1)) * 0.25f;
        t2[m] = tm * tm;
      }
      #pragma unroll
      for (int j = 0; j < 4; ++j) {
        const float ov = valid ? (acc[i][j][r] - mu) * iv * gl[j] + bl[j] : 0.f;
        #pragma unroll
        for (int m = 0; m < 4; ++m) pool[m][j] += t2[m] * ov;
      }
    }
  #pragma unroll
  for (int m = 0; m < 4; ++m)
    #pragma unroll
    for (int j = 0; j < 4; ++j) {
      pool[m][j] += __shfl_xor(pool[m][j], 16);
      pool[m][j] += __shfl_xor(pool[m][j], 32);
    }
  const int sc = (m0 >> 6) & 7;
  if ((lane >> 4) == 0) {
    #pragma unroll
    for (int m = 0; m < 4; ++m)
      #pragma unroll
      for (int j = 0; j < 4; ++j)
        Up[(((size_t)b * 8 + sc) * 4 + m) * DMOD + (w * 4 + j) * 16 + cc] =
            pool[m][j];
  }
}

// ---------------- MFMA attention per (bh, q-tile of 128), fp16 ------------------
// T14 async-STAGE split: double-buffered Ks/Vs/Ms; next tile's global loads
// ISSUED at iteration top (in flight during QK+softmax), WRITTEN to LDS after
// softmax, one barrier later. Same-iteration issue->use (no barrier between)
// so the compiler cannot profitably sink the loads (unlike round-1's attempt).
// 2 barriers/iter (was 3). LDS 55.5 KB, 2 blocks/CU.
__global__ __launch_bounds__(256, 2) void k_attn(
    const _Float16* __restrict__ q_, const _Float16* __restrict__ k_,
    const _Float16* __restrict__ vt, const unsigned int* __restrict__ pk,
    _Float16* __restrict__ o) {
  const int L = blockIdx.x;
  const int bh = (L & 7) * 16 + ((L >> 3) & 15);
  const int q0 = (L >> 7) * 128;
  const size_t bhoff = (size_t)bh * 32768;
  __shared__ half8 QP[1088];                    // Q staging, then P
  __shared__ half8 Ks[2][544], Vs[2][544];      // double-buffered K/V tiles
  __shared__ unsigned long long Ms64[2][128];   // double-buffered mask rows
  __shared__ float Ps[4][128];
  __shared__ float lsum[128];
  const int tid = threadIdx.x;
  const int w = tid >> 6;
  const int lane = tid & 63;
  const int l15 = lane & 15;
  const int quad = lane >> 4;
  // stage Q tile: 128 rows x 64 d
  #pragma unroll
  for (int p = 0; p < 4; ++p) {
    const int lin = tid + p * 256;
    const int r = lin >> 3, g = lin & 7;
    const int fi = (r >> 4) * 128 + g * 16 + (r & 15);
    QP[PG(fi)] = *(const half8*)(q_ + bhoff + (size_t)(q0 + r) * 64 + g * 8);
  }
  // loop-invariant staging indices
  int fi_[2]; const _Float16 *ka_[2], *va_[2];
  #pragma unroll
  for (int p = 0; p < 2; ++p) {
    const int lin = tid + p * 256;
    const int r = lin >> 3, g = lin & 7;
    fi_[p] = PG((r >> 4) * 128 + g * 16 + (r & 15));
    ka_[p] = k_ + bhoff + (size_t)r * 64 + g * 8;     // + kc*64 per tile
    va_[p] = vt + bhoff + (size_t)r * 512 + g * 8;    // + kc per tile
  }
  const size_t mb_ = ((size_t)((bh >> 2) << 9) + q0 + (tid >> 1)) * 16 + (tid & 1);
  __syncthreads();                              // Q staged
  half8 qf[8][2];
  #pragma unroll
  for (int ns = 0; ns < 8; ++ns) {
    const int gq = ns * 8 + quad;
    qf[ns][0] = QP[gq * 17 + l15];
    qf[ns][1] = QP[(gq + 4) * 17 + l15];
  }
  // prologue: stage tile 0 into buffer 0
  #pragma unroll
  for (int p = 0; p < 2; ++p) {
    Ks[0][fi_[p]] = *(const half8*)(ka_[p]);
    Vs[0][fi_[p]] = *(const half8*)(va_[p]);
  }
  ((unsigned int*)Ms64[0])[tid] = pk[mb_];
  __syncthreads();                              // tile 0 + qf extraction done
  float4v oacc[8];
  float lsw[8] = {0.f, 0.f, 0.f, 0.f, 0.f, 0.f, 0.f, 0.f};
  #pragma unroll
  for (int ns = 0; ns < 8; ++ns) oacc[ns] = (float4v){0.f, 0.f, 0.f, 0.f};
  const int ga0 = (w * 8 + quad) * 17 + l15;
  const int ga1 = (w * 8 + quad + 4) * 17 + l15;
  for (int t = 0; t < 8; ++t) {
    const int b = t & 1;
    // ISSUE next tile's loads (latency overlaps QK+softmax below)
    half8 kr0, kr1, vr0, vr1; unsigned int mreg = 0;
    if (t < 7) {
      const int kcn = (t + 1) * 64;
      kr0 = *(const half8*)(ka_[0] + (size_t)kcn * 64);
      kr1 = *(const half8*)(ka_[1] + (size_t)kcn * 64);
      vr0 = *(const half8*)(va_[0] + kcn);
      vr1 = *(const half8*)(va_[1] + kcn);
      mreg = pk[mb_ + (kcn >> 5)];
    }
    // QK^T + masked softmax numerator + P write
    const half8 ah0 = Ks[b][ga0], ah1 = Ks[b][ga1];
    #pragma unroll
    for (int ns = 0; ns < 8; ++ns) {
      float4v s = (float4v){0.f, 0.f, 0.f, 0.f};
      s = MFMA16(ah0, qf[ns][0], s);
      s = MFMA16(ah1, qf[ns][1], s);
      const int q = ns * 16 + l15;
      const unsigned long long mrow = Ms64[b][q];
      const unsigned mbits = (unsigned)(mrow >> (w * 16 + quad * 4)) & 15u;
      half4 h4;
      #pragma unroll
      for (int r = 0; r < 4; ++r) {
        const float pe = ((mbits >> r) & 1u) ? __expf(s[r] * 0.125f) : 0.f;
        h4[r] = (_Float16)pe;
        lsw[ns] += pe;
      }
      const int hb = ((ns * 8 + w * 2 + (quad >> 1)) * 17 + l15) * 8 + (quad & 1) * 4;
      *(half4*)((_Float16*)QP + hb) = h4;
    }
    // WRITE prefetched tile t+1 to the other buffer
    if (t < 7) {
      Ks[b ^ 1][fi_[0]] = kr0;
      Ks[b ^ 1][fi_[1]] = kr1;
      Vs[b ^ 1][fi_[0]] = vr0;
      Vs[b ^ 1][fi_[1]] = vr1;
      ((unsigned int*)Ms64[b ^ 1])[tid] = mreg;
    }
    __syncthreads();                            // barrier1: P + next tile ready
    const half8 vh0 = Vs[b][ga0], vh1 = Vs[b][ga1];
    #pragma unroll
    for (int ns = 0; ns < 8; ++ns) {
      const int pb0 = (ns * 8 + quad) * 17 + l15;
      const int pb1 = (ns * 8 + quad + 4) * 17 + l15;
      oacc[ns] = MFMA16(vh0, QP[pb0], oacc[ns]);
      oacc[ns] = MFMA16(vh1, QP[pb1], oacc[ns]);
    }
    __syncthreads();                            // barrier2: QP/Vs[b] free
  }
  #pragma unroll
  for (int ns = 0; ns < 8; ++ns) {
    lsw[ns] += __shfl_xor(lsw[ns], 16);
    lsw[ns] += __shfl_xor(lsw[ns], 32);
  }
  if (quad == 0) {
    #pragma unroll
    for (int ns = 0; ns < 8; ++ns) Ps[w][ns * 16 + l15] = lsw[ns];
  }
  __syncthreads();
  if (tid < 128) lsum[tid] = Ps[0][tid] + Ps[1][tid] + Ps[2][tid] + Ps[3][tid];
  __syncthreads();
  // epilogue: restage O tile [128 q][64 d] in LDS (stride 68), full-line stores
  const int b = bh >> 2, h = bh & 3;
  _Float16* Ot = (_Float16*)QP;                 // 128*68 = 8704 halfs = QP exactly
  #pragma unroll
  for (int ns = 0; ns < 8; ++ns) {
    const int q = ns * 16 + l15;
    const float inv = 1.0f / lsum[q];
    half4 h4;
    #pragma unroll
    for (int r = 0; r < 4; ++r) h4[r] = (_Float16)(oacc[ns][r] * inv);
    *(half4*)&Ot[q * 68 + w * 16 + quad * 4] = h4;
  }
  __syncthreads();
  #pragma unroll
  for (int e = 0; e < 4; ++e) {
    const int idx = tid + e * 256;
    const int qq = idx >> 3, g = idx & 7;
    *(half8*)(o + ((size_t)(b * SLEN + q0 + qq)) * DMOD + h * HDIM + g * 8) =
        *(const half8*)&Ot[qq * 68 + g * 8];
  }
}

// ---------------- final [32,1024] @ [1024,2]^T + bias (8 s-chunks) --------------
__global__ __launch_bounds__(256) void k_out(
    const float* __restrict__ Up, const float* __restrict__ ow,
    const float* __restrict__ ob, float* __restrict__ out) {
  const int b = blockIdx.x;
  const int tid = threadIdx.x;
  const int w = tid >> 6;
  const int lane = tid & 63;
  __shared__ float rr[8];
  float4 s = {0.f, 0.f, 0.f, 0.f};
  #pragma unroll
  for (int c = 0; c < 8; ++c) {
    const float4 u = *(const float4*)(Up + ((size_t)b * 8 + c) * 1024 + tid * 4);
    s.x += u.x; s.y += u.y; s.z += u.z; s.w += u.w;
  }
  const float4 w0 = *(const float4*)(ow + tid * 4);
  const float4 w1 = *(const float4*)(ow + 1024 + tid * 4);
  float acc0 = s.x * w0.x + s.y * w0.y + s.z * w0.z + s.w * w0.w;
  float acc1 = s.x * w1.x + s.y * w1.y + s.z * w1.z + s.w * w1.w;
  #pragma unroll
  for (int off = 32; off > 0; off >>= 1) {
    acc0 += __shfl_xor(acc0, off);
    acc1 += __shfl_xor(acc1, off);
  }
  if (lane == 0) { rr[w] = acc0; rr[4 + w] = acc1; }
  __syncthreads();
  if (tid == 0) {
    out[b * 2 + 0] = rr[0] + rr[1] + rr[2] + rr[3] + ob[0];
    out[b * 2 + 1] = rr[4] + rr[5] + rr[6] + rr[7] + ob[1];
  }
}

extern "C" void kernel_launch(void* const* d_in, const int* in_sizes, int n_in,
                              void* d_out, int out_size, void* d_ws, size_t ws_size,
                              hipStream_t stream) {
  const int* seqs     = (const int*)d_in[0];
  const int* masks    = (const int*)d_in[1];
  const int* lengths  = (const int*)d_in[2];
  const float* emb    = (const float*)d_in[5];
  const float* bias   = (const float*)d_in[6];
  const float* pe     = (const float*)d_in[7];
  const float* Wq     = (const float*)d_in[8];
  const float* Wk     = (const float*)d_in[9];
  const float* Wv     = (const float*)d_in[10];
  const float* Wfc    = (const float*)d_in[11];
  const float* ln_g   = (const float*)d_in[12];
  const float* ln_b   = (const float*)d_in[13];
  const float* out_w  = (const float*)d_in[14];
  const float* out_b  = (const float*)d_in[15];
  float* outp = (float*)d_out;

  const size_t NE = (size_t)BSZ * SLEN * DMOD;   // 4,194,304
  _Float16* q = (_Float16*)d_ws;
  _Float16* k = q + NE;
  _Float16* v = k + NE;
  _Float16* vt = v + NE;
  _Float16* x = vt + NE;
  _Float16* o = x + NE;
  _Float16* wh = o + NE;                         // 4*65536 halfs
  unsigned int* pk = (unsigned int*)(wh + 4 * 65536);
  float* Up = (float*)(pk + BSZ * SLEN * 16);    // [32][8][4][256] fp32 = 1 MB
  // fp16 emb table (10.24 MB) aliases q+k: dead before gemm_qkv writes them
  _Float16* embh = (_Float16*)d_ws;

  k_cast<<<2628, 256, 0, stream>>>(Wq, Wk, Wv, Wfc, emb, wh, embh);
  k_embmask<<<BSZ * SLEN / 8, 256, 0, stream>>>(seqs, lengths, embh, bias, pe, x,
                                                masks, pk);
  k_gemm_qkv<<<dim3(128, 2, 3), 256, 0, stream>>>(x, wh, q, k, v);
  k_vt<<<dim3(BSZ * NH, 8), 256, 0, stream>>>(v, vt);
  k_attn<<<BSZ * NH * (SLEN / 128), 256, 0, stream>>>(q, k, vt, pk, o);
  k_fcln<<<256, 256, 0, stream>>>(o, wh + 3 * 65536, x, lengths, ln_g, ln_b, Up);
  k_out<<<BSZ, 256, 0, stream>>>(Up, out_w, out_b, outp);
}

// Round 12
// 202.874 us; speedup vs baseline: 1.1022x; 1.0370x over previous
//
#include <hip/hip_runtime.h>

#define BSZ 32
#define SLEN 512
#define CLEN 20
#define DMOD 256
#define NH 4
#define HDIM 64

typedef _Float16 half8 __attribute__((ext_vector_type(8)));
typedef _Float16 half4 __attribute__((ext_vector_type(4)));
typedef float float4v __attribute__((ext_vector_type(4)));

#define MFMA16(a, b, c) __builtin_amdgcn_mfma_f32_16x16x32_f16(a, b, c, 0, 0, 0)
// padded half8 index: groups of 16 half8 get stride 17 (breaks 256B-stride conflicts)
#define PG(fi) ((((fi) >> 4) * 17) + ((fi) & 15))

// ---------------- merged fp32->fp16 cast: 4 weight mats + embedding table ------
__global__ __launch_bounds__(256) void k_cast(
    const float* __restrict__ W0, const float* __restrict__ W1,
    const float* __restrict__ W2, const float* __restrict__ W3,
    const float* __restrict__ emb,
    _Float16* __restrict__ wh, _Float16* __restrict__ embh) {
  const int bid = blockIdx.x;
  const float* src;
  _Float16* dst;
  int idx;
  if (bid < 128) {
    const int z = bid >> 5;
    src = (z == 0) ? W0 : (z == 1) ? W1 : (z == 2) ? W2 : W3;
    dst = wh + (size_t)z * 65536;
    idx = ((bid & 31) * 256 + threadIdx.x) * 8;
  } else {
    src = emb;
    dst = embh;
    idx = ((bid - 128) * 256 + threadIdx.x) * 8;
  }
  float v[8];
  *(float4*)v = *(const float4*)(src + idx);
  *(float4*)(v + 4) = *(const float4*)(src + idx + 4);
  half8 h;
  #pragma unroll
  for (int i = 0; i < 8; ++i) h[i] = (_Float16)v[i];
  *(half8*)(dst + idx) = h;
}

// ---------------- fused: embedding sum + pos-enc -> fp16, AND mask bit-pack -----
// MLP-deepened: all 20 gathers issued into registers BEFORE the accumulate
// (same summation order -> bit-identical); mask loads likewise preloaded.
__global__ __launch_bounds__(256) void k_embmask(
    const int* __restrict__ seqs, const int* __restrict__ lengths,
    const _Float16* __restrict__ embh, const float* __restrict__ bias,
    const float* __restrict__ pe, _Float16* __restrict__ x,
    const int* __restrict__ masks, unsigned int* __restrict__ pk) {
  const int row0 = blockIdx.x * 8;
  const int sub = threadIdx.x >> 5;
  const int hl = threadIdx.x & 31;
  const int row = row0 + sub;
  const int b = row >> 9, s = row & 511;
  __shared__ int codes[8][CLEN];
  if (threadIdx.x < 8 * CLEN)
    codes[threadIdx.x / CLEN][threadIdx.x % CLEN] = seqs[row0 * CLEN + threadIdx.x];
  __syncthreads();
  const int pos = (s < lengths[b]) ? (s + 1) : 0;
  const int d = hl * 8;
  // issue all 20 independent gathers first (20-deep MLP)
  half8 ev[CLEN];
  #pragma unroll
  for (int c = 0; c < CLEN; ++c)
    ev[c] = *(const half8*)(embh + (size_t)codes[sub][c] * DMOD + d);
  float acc[8];
  *(float4*)acc = *(const float4*)(bias + d);
  *(float4*)(acc + 4) = *(const float4*)(bias + d + 4);
  const float4 pv0 = *(const float4*)(pe + (size_t)pos * DMOD + d);
  const float4 pv1 = *(const float4*)(pe + (size_t)pos * DMOD + d + 4);
  acc[0] += pv0.x; acc[1] += pv0.y; acc[2] += pv0.z; acc[3] += pv0.w;
  acc[4] += pv1.x; acc[5] += pv1.y; acc[6] += pv1.z; acc[7] += pv1.w;
  #pragma unroll
  for (int c = 0; c < CLEN; ++c) {
    #pragma unroll
    for (int i = 0; i < 8; ++i) acc[i] += (float)ev[c][i];
  }
  half8 hv;
  #pragma unroll
  for (int i = 0; i < 8; ++i) hv[i] = (_Float16)acc[i];
  *(half8*)(x + (size_t)row * DMOD + d) = hv;
  // ---- phase 2: mask bit-pack (preload all 16 values, then ballots) ----
  const int wv = threadIdx.x >> 6;
  const int lane = threadIdx.x & 63;
  int mv[16];
  #pragma unroll
  for (int p = 0; p < 16; ++p) {
    const int it = wv + p * 4;
    const int r = row0 + (it >> 3);
    const int chunk = it & 7;
    mv[p] = masks[(size_t)r * SLEN + chunk * 64 + lane];
  }
  #pragma unroll
  for (int p = 0; p < 16; ++p) {
    const int it = wv + p * 4;
    const int r = row0 + (it >> 3);
    const int chunk = it & 7;
    const unsigned long long bal = __ballot(mv[p] != 0);
    if (lane == 0) {
      pk[(size_t)r * 16 + chunk * 2]     = (unsigned int)bal;
      pk[(size_t)r * 16 + chunk * 2 + 1] = (unsigned int)(bal >> 32);
    }
  }
}

// ---------------- QKV GEMM: fp16 MFMA, prefetch, vectorized epilogue ------------
__global__ __launch_bounds__(256) void k_gemm_qkv(
    const _Float16* __restrict__ A, const _Float16* __restrict__ Wb,
    _Float16* __restrict__ q, _Float16* __restrict__ k, _Float16* __restrict__ v) {
  const int z = blockIdx.z;
  _Float16* Cb = (z == 0) ? q : (z == 1) ? k : v;
  const _Float16* w_ = Wb + (size_t)z * 65536;
  const int m0 = blockIdx.x * 128;
  const int n0 = blockIdx.y * 128;
  const int tid = threadIdx.x;
  const int lane = tid & 63;
  const int w = tid >> 6;
  const int wm = (w >> 1) * 4;
  const int wn = (w & 1) * 4;
  __shared__ _Float16 smem[8704];
  half8* As = (half8*)(smem);
  half8* Ws = (half8*)(smem + 4096);
  float4v acc[4][4];
  #pragma unroll
  for (int i = 0; i < 4; ++i)
    #pragma unroll
    for (int j = 0; j < 4; ++j)
      acc[i][j] = (float4v){0.f, 0.f, 0.f, 0.f};
  int li_[2]; size_t ga_[2], gw_[2];
  #pragma unroll
  for (int p = 0; p < 2; ++p) {
    const int c = tid + p * 256;
    const int r = c & 127, qd = c >> 7;
    li_[p] = (r >> 4) * 64 + qd * 16 + (r & 15);
    ga_[p] = (size_t)(m0 + r) * DMOD + qd * 8;
    gw_[p] = (size_t)(n0 + r) * DMOD + qd * 8;
  }
  half8 pa[2], pw[2];
  #pragma unroll
  for (int p = 0; p < 2; ++p) {
    pa[p] = *(const half8*)(A + ga_[p]);
    pw[p] = *(const half8*)(w_ + gw_[p]);
  }
  for (int k0 = 0; k0 < DMOD; k0 += 32) {
    #pragma unroll
    for (int p = 0; p < 2; ++p) {
      As[li_[p]] = pa[p];
      Ws[li_[p]] = pw[p];
    }
    __syncthreads();
    if (k0 + 32 < DMOD) {
      #pragma unroll
      for (int p = 0; p < 2; ++p) {
        pa[p] = *(const half8*)(A + ga_[p] + k0 + 32);
        pw[p] = *(const half8*)(w_ + gw_[p] + k0 + 32);
      }
    }
    half8 af[4], wf[4];
    #pragma unroll
    for (int i = 0; i < 4; ++i) {
      af[i] = As[(wm + i) * 64 + lane];
      wf[i] = Ws[(wn + i) * 64 + lane];
    }
    #pragma unroll
    for (int i = 0; i < 4; ++i)
      #pragma unroll
      for (int j = 0; j < 4; ++j)
        acc[i][j] = MFMA16(af[i], wf[j], acc[i][j]);
    __syncthreads();
  }
  const int cr = (lane >> 4) * 4;
  const int cc = lane & 15;
  _Float16* Eh = smem;
  #pragma unroll
  for (int ip = 0; ip < 4; ++ip) {
    #pragma unroll
    for (int j = 0; j < 4; ++j) {
      const int col = (wn + j) * 16 + cc;
      #pragma unroll
      for (int r = 0; r < 4; ++r)
        Eh[((w >> 1) * 16 + cr + r) * 136 + col] = (_Float16)acc[ip][j][r];
    }
    __syncthreads();
    #pragma unroll
    for (int e = 0; e < 2; ++e) {
      const int idx = tid + e * 256;
      const int lr = idx >> 4;
      const int cg = idx & 15;
      const int gr = m0 + (lr >> 4) * 64 + ip * 16 + (lr & 15);
      *(half8*)(Cb + (size_t)gr * DMOD + n0 + cg * 8) =
          *(const half8*)&Eh[lr * 136 + cg * 8];
    }
    __syncthreads();
  }
}

// ---------------- per-bh transpose: v[bh][s][d] -> vt[bh][d][s] -----------------
__global__ __launch_bounds__(256) void k_vt(
    const _Float16* __restrict__ v, _Float16* __restrict__ vt) {
  const int bh = blockIdx.x;
  const size_t off = (size_t)bh * 32768;
  __shared__ _Float16 Th[64][66];
  const int tid = threadIdx.x;
  const int sc = blockIdx.y * 64;
  #pragma unroll
  for (int p = 0; p < 2; ++p) {
    const int lin = tid + p * 256;
    const int r = lin >> 3, g = lin & 7;
    *(half8*)&Th[r][g * 8] = *(const half8*)(v + off + (size_t)(sc + r) * 64 + g * 8);
  }
  __syncthreads();
  #pragma unroll
  for (int p = 0; p < 2; ++p) {
    const int lin = tid + p * 256;
    const int d = lin >> 3, sg = lin & 7;
    half8 hv;
    #pragma unroll
    for (int j = 0; j < 8; ++j) hv[j] = Th[sg * 8 + j][d];
    *(half8*)(vt + off + (size_t)d * 512 + sc + sg * 8) = hv;
  }
}

// ---------------- fused FC GEMM + layer norm + pooling --------------------------
__global__ __launch_bounds__(256) void k_fcln(
    const _Float16* __restrict__ A, const _Float16* __restrict__ w_,
    const _Float16* __restrict__ res, const int* __restrict__ lengths,
    const float* __restrict__ g, const float* __restrict__ bb,
    float* __restrict__ Up) {
  const int m0 = blockIdx.x * 64;
  const int b = m0 >> 9;
  const int s0 = m0 & 511;
  const int tid = threadIdx.x;
  const int lane = tid & 63;
  const int w = tid >> 6;
  __shared__ half8 As[256], Ws[1024];
  __shared__ float Rs[4][64], Rq[4][64];
  __shared__ float Fmu[64], Fiv[64];
  float4v acc[4][4];
  #pragma unroll
  for (int i = 0; i < 4; ++i)
    #pragma unroll
    for (int j = 0; j < 4; ++j)
      acc[i][j] = (float4v){0.f, 0.f, 0.f, 0.f};
  const int ra = tid & 63, qa = tid >> 6;
  const int li_a = (ra >> 4) * 64 + qa * 16 + (ra & 15);
  const size_t ga_ = (size_t)(m0 + ra) * DMOD + qa * 8;
  int li_w[4]; size_t gw_[4];
  #pragma unroll
  for (int p = 0; p < 4; ++p) {
    const int c = tid + p * 256;
    const int rw = c & 255, qw = c >> 8;
    li_w[p] = (rw >> 4) * 64 + qw * 16 + (rw & 15);
    gw_[p] = (size_t)rw * DMOD + qw * 8;
  }
  half8 pa = *(const half8*)(A + ga_);
  half8 pw[4];
  #pragma unroll
  for (int p = 0; p < 4; ++p) pw[p] = *(const half8*)(w_ + gw_[p]);
  for (int k0 = 0; k0 < DMOD; k0 += 32) {
    As[li_a] = pa;
    #pragma unroll
    for (int p = 0; p < 4; ++p) Ws[li_w[p]] = pw[p];
    __syncthreads();
    if (k0 + 32 < DMOD) {
      pa = *(const half8*)(A + ga_ + k0 + 32);
      #pragma unroll
      for (int p = 0; p < 4; ++p) pw[p] = *(const half8*)(w_ + gw_[p] + k0 + 32);
    }
    half8 af[4], wf[4];
    #pragma unroll
    for (int i = 0; i < 4; ++i) {
      af[i] = As[i * 64 + lane];
      wf[i] = Ws[(w * 4 + i) * 64 + lane];
    }
    #pragma unroll
    for (int i = 0; i < 4; ++i)
      #pragma unroll
      for (int j = 0; j < 4; ++j)
        acc[i][j] = MFMA16(af[i], wf[j], acc[i][j]);
    __syncthreads();
  }
  const int cr = (lane >> 4) * 4;
  const int cc = lane & 15;
  const int l15 = cc;
  #pragma unroll
  for (int i = 0; i < 4; ++i)
    #pragma unroll
    for (int j = 0; j < 4; ++j) {
      const int col = (w * 4 + j) * 16 + cc;
      #pragma unroll
      for (int r = 0; r < 4; ++r)
        acc[i][j][r] += (float)res[(size_t)(m0 + i * 16 + cr + r) * DMOD + col];
    }
  float S[4][4], Q2[4][4];
  #pragma unroll
  for (int i = 0; i < 4; ++i)
    #pragma unroll
    for (int r = 0; r < 4; ++r) {
      float s = 0.f, q2 = 0.f;
      #pragma unroll
      for (int j = 0; j < 4; ++j) {
        const float v = acc[i][j][r];
        s += v; q2 += v * v;
      }
      #pragma unroll
      for (int off = 1; off <= 8; off <<= 1) {
        s += __shfl_xor(s, off);
        q2 += __shfl_xor(q2, off);
      }
      S[i][r] = s; Q2[i][r] = q2;
    }
  if (l15 == 0) {
    #pragma unroll
    for (int i = 0; i < 4; ++i)
      #pragma unroll
      for (int r = 0; r < 4; ++r) {
        Rs[w][i * 16 + cr + r] = S[i][r];
        Rq[w][i * 16 + cr + r] = Q2[i][r];
      }
  }
  __syncthreads();
  if (tid < 64) {
    const float s = Rs[0][tid] + Rs[1][tid] + Rs[2][tid] + Rs[3][tid];
    const float q2 = Rq[0][tid] + Rq[1][tid] + Rq[2][tid] + Rq[3][tid];
    const float mu = s * (1.0f / DMOD);
    Fmu[tid] = mu;
    Fiv[tid] = rsqrtf(q2 * (1.0f / DMOD) - mu * mu + 1e-5f);
  }
  __syncthreads();
  const int len = lengths[b];
  const float inv4 = 4.0f / (float)len;
  float gl[4], bl[4];
  #pragma unroll
  for (int j = 0; j < 4; ++j) {
    const int col = (w * 4 + j) * 16 + cc;
    gl[j] = g[col]; bl[j] = bb[col];
  }
  float pool[4][4] = {};
  #pragma unroll
  for (int i = 0; i < 4; ++i)
    #pragma unroll
    for (int r = 0; r < 4; ++r) {
      const int row_l = i * 16 + cr + r;
      const int sg = s0 + row_l;
      const bool valid = sg < len;
      const float mu = Fmu[row_l], iv = Fiv[row_l];
      const float sv = (float)(sg + 1) * inv4;
      float t2[4];
      #pragma unroll
      for (int m = 0; m < 4; ++m) {
        const float tm = 1.0f - fabsf(sv - (float)(m + 1)) * 0.25f;
        t2[m] = tm * tm;
      }
      #pragma unroll
      for (int j = 0; j < 4; ++j) {
        const float ov = valid ? (acc[i][j][r] - mu) * iv * gl[j] + bl[j] : 0.f;
        #pragma unroll
        for (int m = 0; m < 4; ++m) pool[m][j] += t2[m] * ov;
      }
    }
  #pragma unroll
  for (int m = 0; m < 4; ++m)
    #pragma unroll
    for (int j = 0; j < 4; ++j) {
      pool[m][j] += __shfl_xor(pool[m][j], 16);
      pool[m][j] += __shfl_xor(pool[m][j], 32);
    }
  const int sc = (m0 >> 6) & 7;
  if ((lane >> 4) == 0) {
    #pragma unroll
    for (int m = 0; m < 4; ++m)
      #pragma unroll
      for (int j = 0; j < 4; ++j)
        Up[(((size_t)b * 8 + sc) * 4 + m) * DMOD + (w * 4 + j) * 16 + cc] =
            pool[m][j];
  }
}

// ---------------- MFMA attention per (bh, q-tile of 128), fp16 ------------------
// T14 async-STAGE split (verified round 11): 2 barriers/iter, dbuf K/V/mask.
__global__ __launch_bounds__(256, 2) void k_attn(
    const _Float16* __restrict__ q_, const _Float16* __restrict__ k_,
    const _Float16* __restrict__ vt, const unsigned int* __restrict__ pk,
    _Float16* __restrict__ o) {
  const int L = blockIdx.x;
  const int bh = (L & 7) * 16 + ((L >> 3) & 15);
  const int q0 = (L >> 7) * 128;
  const size_t bhoff = (size_t)bh * 32768;
  __shared__ half8 QP[1088];                    // Q staging, then P
  __shared__ half8 Ks[2][544], Vs[2][544];      // double-buffered K/V tiles
  __shared__ unsigned long long Ms64[2][128];   // double-buffered mask rows
  __shared__ float Ps[4][128];
  __shared__ float lsum[128];
  const int tid = threadIdx.x;
  const int w = tid >> 6;
  const int lane = tid & 63;
  const int l15 = lane & 15;
  const int quad = lane >> 4;
  // stage Q tile: 128 rows x 64 d
  #pragma unroll
  for (int p = 0; p < 4; ++p) {
    const int lin = tid + p * 256;
    const int r = lin >> 3, g = lin & 7;
    const int fi = (r >> 4) * 128 + g * 16 + (r & 15);
    QP[PG(fi)] = *(const half8*)(q_ + bhoff + (size_t)(q0 + r) * 64 + g * 8);
  }
  // loop-invariant staging indices
  int fi_[2]; const _Float16 *ka_[2], *va_[2];
  #pragma unroll
  for (int p = 0; p < 2; ++p) {
    const int lin = tid + p * 256;
    const int r = lin >> 3, g = lin & 7;
    fi_[p] = PG((r >> 4) * 128 + g * 16 + (r & 15));
    ka_[p] = k_ + bhoff + (size_t)r * 64 + g * 8;     // + kc*64 per tile
    va_[p] = vt + bhoff + (size_t)r * 512 + g * 8;    // + kc per tile
  }
  const size_t mb_ = ((size_t)((bh >> 2) << 9) + q0 + (tid >> 1)) * 16 + (tid & 1);
  __syncthreads();                              // Q staged
  half8 qf[8][2];
  #pragma unroll
  for (int ns = 0; ns < 8; ++ns) {
    const int gq = ns * 8 + quad;
    qf[ns][0] = QP[gq * 17 + l15];
    qf[ns][1] = QP[(gq + 4) * 17 + l15];
  }
  // prologue: stage tile 0 into buffer 0
  #pragma unroll
  for (int p = 0; p < 2; ++p) {
    Ks[0][fi_[p]] = *(const half8*)(ka_[p]);
    Vs[0][fi_[p]] = *(const half8*)(va_[p]);
  }
  ((unsigned int*)Ms64[0])[tid] = pk[mb_];
  __syncthreads();                              // tile 0 + qf extraction done
  float4v oacc[8];
  float lsw[8] = {0.f, 0.f, 0.f, 0.f, 0.f, 0.f, 0.f, 0.f};
  #pragma unroll
  for (int ns = 0; ns < 8; ++ns) oacc[ns] = (float4v){0.f, 0.f, 0.f, 0.f};
  const int ga0 = (w * 8 + quad) * 17 + l15;
  const int ga1 = (w * 8 + quad + 4) * 17 + l15;
  for (int t = 0; t < 8; ++t) {
    const int b = t & 1;
    // ISSUE next tile's loads (latency overlaps QK+softmax below)
    half8 kr0, kr1, vr0, vr1; unsigned int mreg = 0;
    if (t < 7) {
      const int kcn = (t + 1) * 64;
      kr0 = *(const half8*)(ka_[0] + (size_t)kcn * 64);
      kr1 = *(const half8*)(ka_[1] + (size_t)kcn * 64);
      vr0 = *(const half8*)(va_[0] + kcn);
      vr1 = *(const half8*)(va_[1] + kcn);
      mreg = pk[mb_ + (kcn >> 5)];
    }
    // QK^T + masked softmax numerator + P write
    const half8 ah0 = Ks[b][ga0], ah1 = Ks[b][ga1];
    #pragma unroll
    for (int ns = 0; ns < 8; ++ns) {
      float4v s = (float4v){0.f, 0.f, 0.f, 0.f};
      s = MFMA16(ah0, qf[ns][0], s);
      s = MFMA16(ah1, qf[ns][1], s);
      const int q = ns * 16 + l15;
      const unsigned long long mrow = Ms64[b][q];
      const unsigned mbits = (unsigned)(mrow >> (w * 16 + quad * 4)) & 15u;
      half4 h4;
      #pragma unroll
      for (int r = 0; r < 4; ++r) {
        const float pe = ((mbits >> r) & 1u) ? __expf(s[r] * 0.125f) : 0.f;
        h4[r] = (_Float16)pe;
        lsw[ns] += pe;
      }
      const int hb = ((ns * 8 + w * 2 + (quad >> 1)) * 17 + l15) * 8 + (quad & 1) * 4;
      *(half4*)((_Float16*)QP + hb) = h4;
    }
    // WRITE prefetched tile t+1 to the other buffer
    if (t < 7) {
      Ks[b ^ 1][fi_[0]] = kr0;
      Ks[b ^ 1][fi_[1]] = kr1;
      Vs[b ^ 1][fi_[0]] = vr0;
      Vs[b ^ 1][fi_[1]] = vr1;
      ((unsigned int*)Ms64[b ^ 1])[tid] = mreg;
    }
    __syncthreads();                            // barrier1: P + next tile ready
    const half8 vh0 = Vs[b][ga0], vh1 = Vs[b][ga1];
    #pragma unroll
    for (int ns = 0; ns < 8; ++ns) {
      const int pb0 = (ns * 8 + quad) * 17 + l15;
      const int pb1 = (ns * 8 + quad + 4) * 17 + l15;
      oacc[ns] = MFMA16(vh0, QP[pb0], oacc[ns]);
      oacc[ns] = MFMA16(vh1, QP[pb1], oacc[ns]);
    }
    __syncthreads();                            // barrier2: QP/Vs[b] free
  }
  #pragma unroll
  for (int ns = 0; ns < 8; ++ns) {
    lsw[ns] += __shfl_xor(lsw[ns], 16);
    lsw[ns] += __shfl_xor(lsw[ns], 32);
  }
  if (quad == 0) {
    #pragma unroll
    for (int ns = 0; ns < 8; ++ns) Ps[w][ns * 16 + l15] = lsw[ns];
  }
  __syncthreads();
  if (tid < 128) lsum[tid] = Ps[0][tid] + Ps[1][tid] + Ps[2][tid] + Ps[3][tid];
  __syncthreads();
  // epilogue: restage O tile [128 q][64 d] in LDS (stride 68), full-line stores
  const int b = bh >> 2, h = bh & 3;
  _Float16* Ot = (_Float16*)QP;                 // 128*68 = 8704 halfs = QP exactly
  #pragma unroll
  for (int ns = 0; ns < 8; ++ns) {
    const int q = ns * 16 + l15;
    const float inv = 1.0f / lsum[q];
    half4 h4;
    #pragma unroll
    for (int r = 0; r < 4; ++r) h4[r] = (_Float16)(oacc[ns][r] * inv);
    *(half4*)&Ot[q * 68 + w * 16 + quad * 4] = h4;
  }
  __syncthreads();
  #pragma unroll
  for (int e = 0; e < 4; ++e) {
    const int idx = tid + e * 256;
    const int qq = idx >> 3, g = idx & 7;
    *(half8*)(o + ((size_t)(b * SLEN + q0 + qq)) * DMOD + h * HDIM + g * 8) =
        *(const half8*)&Ot[qq * 68 + g * 8];
  }
}

// ---------------- final [32,1024] @ [1024,2]^T + bias (8 s-chunks) --------------
__global__ __launch_bounds__(256) void k_out(
    const float* __restrict__ Up, const float* __restrict__ ow,
    const float* __restrict__ ob, float* __restrict__ out) {
  const int b = blockIdx.x;
  const int tid = threadIdx.x;
  const int w = tid >> 6;
  const int lane = tid & 63;
  __shared__ float rr[8];
  float4 s = {0.f, 0.f, 0.f, 0.f};
  #pragma unroll
  for (int c = 0; c < 8; ++c) {
    const float4 u = *(const float4*)(Up + ((size_t)b * 8 + c) * 1024 + tid * 4);
    s.x += u.x; s.y += u.y; s.z += u.z; s.w += u.w;
  }
  const float4 w0 = *(const float4*)(ow + tid * 4);
  const float4 w1 = *(const float4*)(ow + 1024 + tid * 4);
  float acc0 = s.x * w0.x + s.y * w0.y + s.z * w0.z + s.w * w0.w;
  float acc1 = s.x * w1.x + s.y * w1.y + s.z * w1.z + s.w * w1.w;
  #pragma unroll
  for (int off = 32; off > 0; off >>= 1) {
    acc0 += __shfl_xor(acc0, off);
    acc1 += __shfl_xor(acc1, off);
  }
  if (lane == 0) { rr[w] = acc0; rr[4 + w] = acc1; }
  __syncthreads();
  if (tid == 0) {
    out[b * 2 + 0] = rr[0] + rr[1] + rr[2] + rr[3] + ob[0];
    out[b * 2 + 1] = rr[4] + rr[5] + rr[6] + rr[7] + ob[1];
  }
}

extern "C" void kernel_launch(void* const* d_in, const int* in_sizes, int n_in,
                              void* d_out, int out_size, void* d_ws, size_t ws_size,
                              hipStream_t stream) {
  const int* seqs     = (const int*)d_in[0];
  const int* masks    = (const int*)d_in[1];
  const int* lengths  = (const int*)d_in[2];
  const float* emb    = (const float*)d_in[5];
  const float* bias   = (const float*)d_in[6];
  const float* pe     = (const float*)d_in[7];
  const float* Wq     = (const float*)d_in[8];
  const float* Wk     = (const float*)d_in[9];
  const float* Wv     = (const float*)d_in[10];
  const float* Wfc    = (const float*)d_in[11];
  const float* ln_g   = (const float*)d_in[12];
  const float* ln_b   = (const float*)d_in[13];
  const float* out_w  = (const float*)d_in[14];
  const float* out_b  = (const float*)d_in[15];
  float* outp = (float*)d_out;

  const size_t NE = (size_t)BSZ * SLEN * DMOD;   // 4,194,304
  _Float16* q = (_Float16*)d_ws;
  _Float16* k = q + NE;
  _Float16* v = k + NE;
  _Float16* vt = v + NE;
  _Float16* x = vt + NE;
  _Float16* o = x + NE;
  _Float16* wh = o + NE;                         // 4*65536 halfs
  unsigned int* pk = (unsigned int*)(wh + 4 * 65536);
  float* Up = (float*)(pk + BSZ * SLEN * 16);    // [32][8][4][256] fp32 = 1 MB
  // fp16 emb table (10.24 MB) aliases q+k: dead before gemm_qkv writes them
  _Float16* embh = (_Float16*)d_ws;

  k_cast<<<2628, 256, 0, stream>>>(Wq, Wk, Wv, Wfc, emb, wh, embh);
  k_embmask<<<BSZ * SLEN / 8, 256, 0, stream>>>(seqs, lengths, embh, bias, pe, x,
                                                masks, pk);
  k_gemm_qkv<<<dim3(128, 2, 3), 256, 0, stream>>>(x, wh, q, k, v);
  k_vt<<<dim3(BSZ * NH, 8), 256, 0, stream>>>(v, vt);
  k_attn<<<BSZ * NH * (SLEN / 128), 256, 0, stream>>>(q, k, vt, pk, o);
  k_fcln<<<256, 256, 0, stream>>>(o, wh + 3 * 65536, x, lengths, ln_g, ln_b, Up);
  k_out<<<BSZ, 256, 0, stream>>>(Up, out_w, out_b, outp);
}